// Round 1
// baseline (28536.096 us; speedup 1.0000x reference)
//
#include <hip/hip_runtime.h>
#include <hip/hip_bf16.h>
#include <cstdio>

// Shapes (fixed by the problem)
#define Bn 2
#define Cn 512
#define Sn 256
#define En 512
// BC = 1024 channels total; per-(b,c): x slab = 256*512 floats, prod slab = 256*256 floats.

// Workspace layout (floats unless noted):
//   [0,512)            : mean[c]
//   [512,1024)         : rstd[c]
//   [1024,2560)        : colsum[3][512] of Q,K,V
//   [4096,135168)      : invsum[(b*256+s)*256+t]
//   float off 262144   : prod/exp buffer, 2*512*256*256 f32 (256 MiB)
//   byte off 1MiB+256MiB: v as bf16 (ushort), 134217728 elems (256 MiB)
static constexpr size_t PROD_FOFF = 262144;
static constexpr size_t VOFF_BYTES = (1ull << 20) + (256ull << 20);
static constexpr size_t WS_NEEDED = VOFF_BYTES + (256ull << 20);

__device__ __forceinline__ unsigned short f2bf(float f) {
  union { __hip_bfloat16 h; unsigned short u; } cv;
  cv.h = __float2bfloat16(f);
  return cv.u;
}
__device__ __forceinline__ float bf2f(unsigned short u) {
  union { unsigned int i; float f; } cv;
  cv.i = ((unsigned int)u) << 16;
  return cv.f;
}

// K0: column sums of Q,K,V -> ws[1024 + m*512 + col]
__global__ void k0_colsum(const float* __restrict__ Q, const float* __restrict__ K,
                          const float* __restrict__ V, float* __restrict__ ws) {
  const int m = blockIdx.x >> 1;
  const int col = ((blockIdx.x & 1) << 8) | threadIdx.x;
  const float* W = (m == 0) ? Q : ((m == 1) ? K : V);
  float s = 0.f;
#pragma unroll 8
  for (int e = 0; e < En; ++e) s += W[(size_t)e * En + col];
  ws[1024 + m * 512 + col] = s;
}

// K1: per-channel mean / rstd over (B,S,E) = 262144 elements
__global__ void k1_stats(const float* __restrict__ x, float* __restrict__ ws) {
  const int c = blockIdx.x, tid = threadIdx.x;
  const float4* p0 = (const float4*)(x + (size_t)c * (Sn * En));
  const float4* p1 = (const float4*)(x + (size_t)(Cn + c) * (Sn * En));
  float s1 = 0.f, s2 = 0.f;
  for (int i = tid; i < (Sn * En / 4); i += 256) {
    float4 a = p0[i], b = p1[i];
    s1 += (a.x + a.y) + (a.z + a.w) + (b.x + b.y) + (b.z + b.w);
    s2 += (a.x * a.x + a.y * a.y) + (a.z * a.z + a.w * a.w) +
          (b.x * b.x + b.y * b.y) + (b.z * b.z + b.w * b.w);
  }
  __shared__ float r1[256], r2[256];
  r1[tid] = s1; r2[tid] = s2;
  __syncthreads();
  for (int off = 128; off > 0; off >>= 1) {
    if (tid < off) { r1[tid] += r1[tid + off]; r2[tid] += r2[tid + off]; }
    __syncthreads();
  }
  if (tid == 0) {
    const float n = (float)(2 * Sn * En);
    float mean = r1[0] / n;
    float var = r2[0] / n - mean * mean;
    ws[c] = mean;
    ws[512 + c] = 1.0f / sqrtf(var + 1e-5f);
  }
}

// K2: per (b,c): q,k f-tiles (fp32, LDS) -> prod accumulation (fp32 regs) ; v -> bf16 global.
// BatchNorm folded: q = rstd*(x . Qcol - mean*colsumQ).
__launch_bounds__(1024)
__global__ void k2_qkvprod(const float* __restrict__ x,
                           const float* __restrict__ Qm,
                           const float* __restrict__ Km,
                           const float* __restrict__ Vm,
                           float* __restrict__ ws,
                           unsigned short* __restrict__ vws) {
  __shared__ float qt[32 * 256];  // [f_local][s], transposed
  __shared__ float kt[32 * 256];
  const int bc = blockIdx.x;
  const int c = bc & 511;
  const int tid = threadIdx.x;
  const float mean = ws[c];
  const float rstd = ws[512 + c];
  const float* __restrict__ xc = x + (size_t)bc * (Sn * En);
  const float* __restrict__ cs = ws + 1024;  // colsums [3][512]
  float* __restrict__ prodc = ws + PROD_FOFF + (size_t)bc * (Sn * Sn);
  unsigned short* __restrict__ vc = vws + (size_t)bc * (Sn * En);

  const int tx = tid & 7;    // f-group: 4 consecutive cols in 32-wide tile
  const int ry = tid >> 3;   // 0..127 row within half
  const int ar = tid >> 5;   // 0..31 (prod row group)
  const int ac = tid & 31;   // 0..31 (prod col group)

  float pacc[2][2][4][4] = {};  // [rowhalf][colhalf][i][j]

  for (int ft = 0; ft < 16; ++ft) {
    const int f0 = ft * 32;
    // ---- step 1: q,k f-tile into LDS (2 row passes of 128 rows) ----
#pragma unroll 1
    for (int pass = 0; pass < 2; ++pass) {
      const int srow = ry + 128 * pass;
      const float* __restrict__ xr = xc + (size_t)srow * En;
      const float* __restrict__ Qp = Qm + f0 + tx * 4;
      const float* __restrict__ Kp = Km + f0 + tx * 4;
      float aq[4] = {0.f, 0.f, 0.f, 0.f}, ak[4] = {0.f, 0.f, 0.f, 0.f};
      for (int e = 0; e < En; e += 2) {
        const float2 xv = *(const float2*)(xr + e);
        const float4 qw0 = *(const float4*)(Qp + (size_t)e * En);
        const float4 kw0 = *(const float4*)(Kp + (size_t)e * En);
        const float4 qw1 = *(const float4*)(Qp + (size_t)(e + 1) * En);
        const float4 kw1 = *(const float4*)(Kp + (size_t)(e + 1) * En);
        aq[0] += xv.x * qw0.x; aq[1] += xv.x * qw0.y; aq[2] += xv.x * qw0.z; aq[3] += xv.x * qw0.w;
        ak[0] += xv.x * kw0.x; ak[1] += xv.x * kw0.y; ak[2] += xv.x * kw0.z; ak[3] += xv.x * kw0.w;
        aq[0] += xv.y * qw1.x; aq[1] += xv.y * qw1.y; aq[2] += xv.y * qw1.z; aq[3] += xv.y * qw1.w;
        ak[0] += xv.y * kw1.x; ak[1] += xv.y * kw1.y; ak[2] += xv.y * kw1.z; ak[3] += xv.y * kw1.w;
      }
#pragma unroll
      for (int j = 0; j < 4; ++j) {
        const int f = tx * 4 + j;
        qt[f * 256 + srow] = rstd * (aq[j] - mean * cs[f0 + f]);
        kt[f * 256 + srow] = rstd * (ak[j] - mean * cs[512 + f0 + f]);
      }
    }
    __syncthreads();
    // ---- step 2: prod[s][t] += sum_f q[s][f]*k[t][f] ----
#pragma unroll 2
    for (int f = 0; f < 32; ++f) {
      const float4 qa = *(const float4*)(qt + f * 256 + ar * 4);
      const float4 qb = *(const float4*)(qt + f * 256 + 128 + ar * 4);
      const float4 ka = *(const float4*)(kt + f * 256 + ac * 4);
      const float4 kb = *(const float4*)(kt + f * 256 + 128 + ac * 4);
      const float qv[8] = {qa.x, qa.y, qa.z, qa.w, qb.x, qb.y, qb.z, qb.w};
      const float kv[8] = {ka.x, ka.y, ka.z, ka.w, kb.x, kb.y, kb.z, kb.w};
#pragma unroll
      for (int i = 0; i < 8; ++i)
#pragma unroll
        for (int j = 0; j < 8; ++j)
          pacc[i >> 2][j >> 2][i & 3][j & 3] += qv[i] * kv[j];
    }
    __syncthreads();
    // ---- step 3: v f-tile straight to global (bf16) ----
#pragma unroll 1
    for (int pass = 0; pass < 2; ++pass) {
      const int srow = ry + 128 * pass;
      const float* __restrict__ xr = xc + (size_t)srow * En;
      const float* __restrict__ Vp = Vm + f0 + tx * 4;
      float av[4] = {0.f, 0.f, 0.f, 0.f};
      for (int e = 0; e < En; e += 2) {
        const float2 xv = *(const float2*)(xr + e);
        const float4 vw0 = *(const float4*)(Vp + (size_t)e * En);
        const float4 vw1 = *(const float4*)(Vp + (size_t)(e + 1) * En);
        av[0] += xv.x * vw0.x; av[1] += xv.x * vw0.y; av[2] += xv.x * vw0.z; av[3] += xv.x * vw0.w;
        av[0] += xv.y * vw1.x; av[1] += xv.y * vw1.y; av[2] += xv.y * vw1.z; av[3] += xv.y * vw1.w;
      }
      ushort4 pk;
      pk.x = f2bf(rstd * (av[0] - mean * cs[1024 + f0 + tx * 4 + 0]));
      pk.y = f2bf(rstd * (av[1] - mean * cs[1024 + f0 + tx * 4 + 1]));
      pk.z = f2bf(rstd * (av[2] - mean * cs[1024 + f0 + tx * 4 + 2]));
      pk.w = f2bf(rstd * (av[3] - mean * cs[1024 + f0 + tx * 4 + 3]));
      *(ushort4*)(vc + (size_t)srow * En + f0 + tx * 4) = pk;
    }
  }
  // ---- write prod (scaled by 1/sqrt(E)) ----
  const float scale = 0.044194173824159216f;  // 1/sqrt(512)
#pragma unroll
  for (int rh = 0; rh < 2; ++rh)
#pragma unroll
    for (int i = 0; i < 4; ++i) {
      const int row = rh * 128 + ar * 4 + i;
#pragma unroll
      for (int ch = 0; ch < 2; ++ch) {
        float4 st;
        st.x = pacc[rh][ch][i][0] * scale;
        st.y = pacc[rh][ch][i][1] * scale;
        st.z = pacc[rh][ch][i][2] * scale;
        st.w = pacc[rh][ch][i][3] * scale;
        *(float4*)(prodc + (size_t)row * 256 + ch * 128 + ac * 4) = st;
      }
    }
}

// K3: softmax over channel dim c (axis 1). One block per (b,s); lane = t.
// Writes exp(p - max) in place and invsum to ws.
__global__ void k3_softmax(float* __restrict__ ws) {
  const int bid = blockIdx.x;  // b*256 + s
  const int b = bid >> 8, s = bid & 255;
  const int t = threadIdx.x;
  float* __restrict__ p =
      ws + PROD_FOFF + (size_t)b * (512ull * 65536) + (size_t)s * 256 + t;
  float m = -3.4e38f;
#pragma unroll 8
  for (int cc = 0; cc < 512; ++cc) m = fmaxf(m, p[(size_t)cc * 65536]);
  float sum = 0.f;
#pragma unroll 4
  for (int cc = 0; cc < 512; ++cc) {
    const float ev = __expf(p[(size_t)cc * 65536] - m);
    p[(size_t)cc * 65536] = ev;
    sum += ev;
  }
  ws[4096 + (size_t)bid * 256 + t] = 1.0f / sum;
}

// K4: out[s][f] = sum_t sm[s][t]*v[t][f] + xn[s][f].  64x256 tile per block, t-tile 32.
__launch_bounds__(256)
__global__ void k4_pv(const float* __restrict__ x,
                      const unsigned short* __restrict__ vws,
                      const float* __restrict__ ws,
                      float* __restrict__ out) {
  __shared__ float smt[32 * 68];   // [tl][r] transposed, stride 68
  __shared__ float vt[32 * 260];   // [tl][fl], stride 260
  const int bid = blockIdx.x;
  const int bc = bid >> 3;
  const int s0 = ((bid >> 1) & 3) * 64;
  const int f0 = (bid & 1) * 256;
  const int b = bc >> 9;
  const int c = bc & 511;
  const int tid = threadIdx.x;
  const int tr = tid >> 5, tc = tid & 31;
  const float* __restrict__ pexp = ws + PROD_FOFF + (size_t)bc * 65536;
  const float* __restrict__ inv = ws + 4096 + (size_t)b * 65536;
  const unsigned short* __restrict__ vc = vws + (size_t)bc * (Sn * En);

  float acc[2][2][4][4] = {};  // rows s0+rh*32+tr*4+i, cols f0+ch*128+tc*4+j

  for (int tt = 0; tt < 8; ++tt) {
    const int t0 = tt * 32;
    // stage sm (normalized) transposed: smt[tl][r]
#pragma unroll
    for (int k = 0; k < 8; ++k) {
      const int idx = tid + 256 * k;
      const int r = idx >> 5, tl = idx & 31;
      const size_t gi = (size_t)(s0 + r) * 256 + t0 + tl;
      smt[tl * 68 + r] = pexp[gi] * inv[gi];
    }
    // stage v tile (bf16 -> f32): vt[tl][fl]
#pragma unroll
    for (int k = 0; k < 8; ++k) {
      const int idx = tid + 256 * k;  // ushort4 group
      const int tl = idx >> 6, g = idx & 63;
      const ushort4 vv = *(const ushort4*)(vc + (size_t)(t0 + tl) * En + f0 + g * 4);
      float4 vf;
      vf.x = bf2f(vv.x); vf.y = bf2f(vv.y); vf.z = bf2f(vv.z); vf.w = bf2f(vv.w);
      *(float4*)(vt + tl * 260 + g * 4) = vf;
    }
    __syncthreads();
#pragma unroll 2
    for (int tl = 0; tl < 32; ++tl) {
      const float4 sa = *(const float4*)(smt + tl * 68 + tr * 4);
      const float4 sb = *(const float4*)(smt + tl * 68 + 32 + tr * 4);
      const float4 va = *(const float4*)(vt + tl * 260 + tc * 4);
      const float4 vb = *(const float4*)(vt + tl * 260 + 128 + tc * 4);
      const float sv[8] = {sa.x, sa.y, sa.z, sa.w, sb.x, sb.y, sb.z, sb.w};
      const float vv[8] = {va.x, va.y, va.z, va.w, vb.x, vb.y, vb.z, vb.w};
#pragma unroll
      for (int i = 0; i < 8; ++i)
#pragma unroll
        for (int j = 0; j < 8; ++j)
          acc[i >> 2][j >> 2][i & 3][j & 3] += sv[i] * vv[j];
    }
    __syncthreads();
  }
  const float mean = ws[c], rstd = ws[512 + c];
#pragma unroll
  for (int rh = 0; rh < 2; ++rh)
#pragma unroll
    for (int i = 0; i < 4; ++i) {
      const int srow = s0 + rh * 32 + tr * 4 + i;
#pragma unroll
      for (int ch = 0; ch < 2; ++ch) {
        const size_t oi =
            (size_t)bc * (Sn * En) + (size_t)srow * En + f0 + ch * 128 + tc * 4;
        const float4 xv = *(const float4*)(x + oi);
        float4 st;
        st.x = acc[rh][ch][i][0] + (xv.x - mean) * rstd;
        st.y = acc[rh][ch][i][1] + (xv.y - mean) * rstd;
        st.z = acc[rh][ch][i][2] + (xv.z - mean) * rstd;
        st.w = acc[rh][ch][i][3] + (xv.w - mean) * rstd;
        *(float4*)(out + oi) = st;
      }
    }
}

extern "C" void kernel_launch(void* const* d_in, const int* in_sizes, int n_in,
                              void* d_out, int out_size, void* d_ws, size_t ws_size,
                              hipStream_t stream) {
  const float* x = (const float*)d_in[0];
  const float* Q = (const float*)d_in[1];
  const float* K = (const float*)d_in[2];
  const float* V = (const float*)d_in[3];
  float* out = (float*)d_out;
  float* ws = (float*)d_ws;
  unsigned short* vws = (unsigned short*)((char*)d_ws + VOFF_BYTES);
  if (ws_size < WS_NEEDED) {
    fprintf(stderr, "kernel_launch: ws_size %zu < needed %zu — expect corruption\n",
            ws_size, WS_NEEDED);
  }
  k0_colsum<<<dim3(6), dim3(256), 0, stream>>>(Q, K, V, ws);
  k1_stats<<<dim3(512), dim3(256), 0, stream>>>(x, ws);
  k2_qkvprod<<<dim3(1024), dim3(1024), 0, stream>>>(x, Q, K, V, ws, vws);
  k3_softmax<<<dim3(512), dim3(256), 0, stream>>>(ws);
  k4_pv<<<dim3(8192), dim3(256), 0, stream>>>(x, vws, ws, out);
}

// Round 2
// 2627.076 us; speedup vs baseline: 10.8623x; 10.8623x over previous
//
#include <hip/hip_runtime.h>
#include <hip/hip_bf16.h>
#include <cstdio>

#define Bn 2
#define Cn 512
#define Sn 256
#define En 512

typedef __attribute__((ext_vector_type(8))) short bf16x8;
typedef __attribute__((ext_vector_type(4))) float f32x4;

// Workspace layout (bytes):
//   [0, 2048)        : mean[512] f32
//   [2048, 4096)     : rstd[512] f32
//   f32 idx 4096..   : invsum[(b*256+s)*256+t]  (512 KiB)
//   byte 1 MiB       : prod f32 [1024][256][256]   (256 MiB)
//   byte 1MiB+256MiB : v bf16 [1024*256][512]      (256 MiB)
//   then AT_hi, AT_lo, VT bf16 (512 KiB each)
static constexpr size_t PROD_B = (1ull << 20);
static constexpr size_t V_B    = PROD_B + (256ull << 20);
static constexpr size_t ATH_B  = V_B + (256ull << 20);
static constexpr size_t ATL_B  = ATH_B + (512ull << 10);
static constexpr size_t VT_B   = ATL_B + (512ull << 10);
static constexpr size_t WS_NEEDED = VT_B + (512ull << 10);
static constexpr size_t PROD_F = PROD_B / 4;  // f32 index 262144 (same as round 1)

__device__ __forceinline__ unsigned short f2bf(float f) {
  union { __hip_bfloat16 h; unsigned short u; } cv;
  cv.h = __float2bfloat16(f);
  return cv.u;
}
__device__ __forceinline__ float bf2f(unsigned short u) {
  union { unsigned int i; float f; } cv;
  cv.i = ((unsigned int)u) << 16;
  return cv.f;
}
__device__ __forceinline__ void split2(float v, unsigned short& h, unsigned short& l) {
  h = f2bf(v);
  l = f2bf(v - bf2f(h));
}
// ushort index of a 4-element (8-byte) group at (row, col-group c4) in a [R][64] ushort
// LDS tile, XOR-swizzled (T2: byte ^= (row&7)<<4) to kill stride-128B bank conflicts.
__device__ __forceinline__ int swz8(int row, int c4) {
  return row * 64 + ((((c4 * 8) ^ ((row & 7) << 4))) >> 1);
}
// MFMA fragment load: 8 consecutive bf16 along k from row `row`, k-chunk = ks*32 + (lane>>4)*8.
__device__ __forceinline__ bf16x8 ldfrag(const unsigned short* arr, int row, int ks, int lane) {
  const int byte = (ks * 64 + ((lane >> 4) << 4)) ^ ((row & 7) << 4);
  return *(const bf16x8*)((const char*)(arr + (size_t)row * 64) + byte);
}
__device__ __forceinline__ f32x4 MFMA(bf16x8 a, bf16x8 b, f32x4 c) {
  return __builtin_amdgcn_mfma_f32_16x16x32_bf16(a, b, c, 0, 0, 0);
}

// ---------------- K1: per-channel mean / rstd ----------------
__global__ void k1_stats(const float* __restrict__ x, float* __restrict__ ws) {
  const int c = blockIdx.x, tid = threadIdx.x;
  const float4* p0 = (const float4*)(x + (size_t)c * (Sn * En));
  const float4* p1 = (const float4*)(x + (size_t)(Cn + c) * (Sn * En));
  float s1 = 0.f, s2 = 0.f;
  for (int i = tid; i < (Sn * En / 4); i += 256) {
    float4 a = p0[i], b = p1[i];
    s1 += (a.x + a.y) + (a.z + a.w) + (b.x + b.y) + (b.z + b.w);
    s2 += (a.x * a.x + a.y * a.y) + (a.z * a.z + a.w * a.w) +
          (b.x * b.x + b.y * b.y) + (b.z * b.z + b.w * b.w);
  }
  __shared__ float r1[256], r2[256];
  r1[tid] = s1; r2[tid] = s2;
  __syncthreads();
  for (int off = 128; off > 0; off >>= 1) {
    if (tid < off) { r1[tid] += r1[tid + off]; r2[tid] += r2[tid + off]; }
    __syncthreads();
  }
  if (tid == 0) {
    const float n = (float)(2 * Sn * En);
    float mean = r1[0] / n;
    float var = r2[0] / n - mean * mean;
    ws[c] = mean;
    ws[512 + c] = 1.0f / sqrtf(var + 1e-5f);
  }
}

// ---------------- kA: AT = (Q·K^T)^T = K·Q^T, split hi/lo bf16; VT = V^T bf16 --------
// block f (512 blocks): AT[f][e] = sum_t K[f][t] * Q[e][t]; VT[f][e] = bf16(V[e][f]).
__global__ void kA(const float* __restrict__ Q, const float* __restrict__ K,
                   const float* __restrict__ V, unsigned short* __restrict__ ATh,
                   unsigned short* __restrict__ ATl, unsigned short* __restrict__ VT) {
  const int f = blockIdx.x, tid = threadIdx.x;
  __shared__ float Kf[512];
  for (int i = tid; i < 512; i += 256) Kf[i] = K[(size_t)f * 512 + i];
  __syncthreads();
#pragma unroll
  for (int half = 0; half < 2; ++half) {
    const int e = tid + half * 256;
    const float* Qe = Q + (size_t)e * 512;
    float acc = 0.f;
    for (int t = 0; t < 512; t += 4) {
      float4 q = *(const float4*)(Qe + t);
      acc += q.x * Kf[t] + q.y * Kf[t + 1] + q.z * Kf[t + 2] + q.w * Kf[t + 3];
    }
    unsigned short h, l;
    split2(acc, h, l);
    ATh[(size_t)f * 512 + e] = h;
    ATl[(size_t)f * 512 + e] = l;
    VT[(size_t)f * 512 + e] = f2bf(V[(size_t)e * 512 + f]);
  }
}

// ---------------- kv_proj: v = xn · V  (bf16 MFMA, hi-only precision) ----------------
// grid (2048, 4): 128 M-rows x 128 N-cols per block, 256 threads (4 waves).
__launch_bounds__(256)
__global__ void kv_proj(const float* __restrict__ x, const unsigned short* __restrict__ VT,
                        const float* __restrict__ ws, unsigned short* __restrict__ vout) {
  __shared__ unsigned short XN[128 * 64];
  __shared__ unsigned short VTs[128 * 64];
  const int mt = blockIdx.x, nt = blockIdx.y;
  const int row0 = mt * 128;
  const int bc = row0 >> 8;
  const int c = bc & 511;
  const float mean = ws[c], rstd = ws[512 + c];
  const int f0 = nt * 128;
  const int tid = threadIdx.x, w = tid >> 6, lane = tid & 63;
  const float* xb = x + (size_t)row0 * 512;

  f32x4 acc[2][8];
#pragma unroll
  for (int i = 0; i < 2; ++i)
#pragma unroll
    for (int j = 0; j < 8; ++j) acc[i][j] = (f32x4){0.f, 0.f, 0.f, 0.f};

  for (int et = 0; et < 8; ++et) {
    const int e0 = et * 64;
    __syncthreads();
    // stage xn rows (hi only): 128x64 elems
#pragma unroll
    for (int i = 0; i < 8; ++i) {
      const int g = tid + i * 256;
      const int r = g >> 4, c4 = g & 15;
      float4 xv = *(const float4*)(xb + (size_t)r * 512 + e0 + c4 * 4);
      ushort4 hv;
      hv.x = f2bf((xv.x - mean) * rstd);
      hv.y = f2bf((xv.y - mean) * rstd);
      hv.z = f2bf((xv.z - mean) * rstd);
      hv.w = f2bf((xv.w - mean) * rstd);
      *(ushort4*)&XN[swz8(r, c4)] = hv;
    }
    // stage VT tile rows f0..f0+127, cols e0..e0+63
#pragma unroll
    for (int i = 0; i < 8; ++i) {
      const int g = tid + i * 256;
      const int r = g >> 4, c4 = g & 15;
      ushort4 v = *(const ushort4*)(VT + (size_t)(f0 + r) * 512 + e0 + c4 * 4);
      *(ushort4*)&VTs[swz8(r, c4)] = v;
    }
    __syncthreads();
#pragma unroll
    for (int ks = 0; ks < 2; ++ks) {
      bf16x8 a0 = ldfrag(XN, w * 32 + (lane & 15), ks, lane);
      bf16x8 a1 = ldfrag(XN, w * 32 + 16 + (lane & 15), ks, lane);
#pragma unroll
      for (int ct = 0; ct < 8; ++ct) {
        bf16x8 b = ldfrag(VTs, ct * 16 + (lane & 15), ks, lane);
        acc[0][ct] = MFMA(a0, b, acc[0][ct]);
        acc[1][ct] = MFMA(a1, b, acc[1][ct]);
      }
    }
  }
#pragma unroll
  for (int rt = 0; rt < 2; ++rt)
#pragma unroll
    for (int ct = 0; ct < 8; ++ct)
#pragma unroll
      for (int r = 0; r < 4; ++r) {
        const int row = row0 + w * 32 + rt * 16 + (lane >> 4) * 4 + r;
        vout[(size_t)row * 512 + f0 + ct * 16 + (lane & 15)] = f2bf(acc[rt][ct][r]);
      }
}

// ---------------- kscores: z = (xn·A)·xn^T / sqrt(E), split-bf16 3-MFMA ----------------
// grid 2048: block = (b,c, s-half). 512 threads = 8 waves; wave w owns z rows w*16..w*16+15.
__launch_bounds__(512)
__global__ void kscores(const float* __restrict__ x, const unsigned short* __restrict__ ATh_g,
                        const unsigned short* __restrict__ ATl_g, const float* __restrict__ ws,
                        float* __restrict__ prod) {
  __shared__ unsigned short XNh[256 * 64], XNl[256 * 64];  // 32 KiB each
  __shared__ unsigned short ATh[64 * 64], ATl[64 * 64];    // 8 KiB each
  __shared__ unsigned short Yh[128 * 64], Yl[128 * 64];    // 16 KiB each  (112 KiB total)
  const int bid = blockIdx.x;
  const int bc = bid >> 1, half = bid & 1;
  const int c = bc & 511;
  const float mean = ws[c], rstd = ws[512 + c];
  const float* xc = x + (size_t)bc * (Sn * En);
  const float* xr = xc + (size_t)half * 128 * 512;  // this block's s rows
  float* prodc = prod + (size_t)bc * 65536 + (size_t)half * 128 * 256;
  const int tid = threadIdx.x, w = tid >> 6, lane = tid & 63;

  f32x4 accz[16];
#pragma unroll
  for (int i = 0; i < 16; ++i) accz[i] = (f32x4){0.f, 0.f, 0.f, 0.f};

  for (int ft = 0; ft < 8; ++ft) {
    const int f0 = ft * 64;
    f32x4 accy[4];
#pragma unroll
    for (int i = 0; i < 4; ++i) accy[i] = (f32x4){0.f, 0.f, 0.f, 0.f};

    // ---- phase 1: y[128][64] = xn_rows · A[:, f0:f0+64]  (loop over e-tiles) ----
    for (int et = 0; et < 8; ++et) {
      const int e0 = et * 64;
      __syncthreads();  // previous readers of XN/AT done
      // stage xn rows 0..127 (hi/lo) from x
#pragma unroll
      for (int i = 0; i < 4; ++i) {
        const int g = tid + i * 512;
        const int r = g >> 4, c4 = g & 15;
        float4 xv = *(const float4*)(xr + (size_t)r * 512 + e0 + c4 * 4);
        ushort4 hv, lv;
        split2((xv.x - mean) * rstd, hv.x, lv.x);
        split2((xv.y - mean) * rstd, hv.y, lv.y);
        split2((xv.z - mean) * rstd, hv.z, lv.z);
        split2((xv.w - mean) * rstd, hv.w, lv.w);
        *(ushort4*)&XNh[swz8(r, c4)] = hv;
        *(ushort4*)&XNl[swz8(r, c4)] = lv;
      }
      // stage AT tile [64 f][64 e] (pre-split bf16 from global)
#pragma unroll
      for (int i = 0; i < 2; ++i) {
        const int g = tid + i * 512;
        const int r = g >> 4, c4 = g & 15;
        ushort4 h = *(const ushort4*)(ATh_g + (size_t)(f0 + r) * 512 + e0 + c4 * 4);
        ushort4 l = *(const ushort4*)(ATl_g + (size_t)(f0 + r) * 512 + e0 + c4 * 4);
        *(ushort4*)&ATh[swz8(r, c4)] = h;
        *(ushort4*)&ATl[swz8(r, c4)] = l;
      }
      __syncthreads();
#pragma unroll
      for (int ks = 0; ks < 2; ++ks) {
        bf16x8 ah = ldfrag(XNh, w * 16 + (lane & 15), ks, lane);
        bf16x8 al = ldfrag(XNl, w * 16 + (lane & 15), ks, lane);
#pragma unroll
        for (int fc = 0; fc < 4; ++fc) {
          bf16x8 bh = ldfrag(ATh, fc * 16 + (lane & 15), ks, lane);
          bf16x8 bl = ldfrag(ATl, fc * 16 + (lane & 15), ks, lane);
          accy[fc] = MFMA(ah, bh, accy[fc]);
          accy[fc] = MFMA(ah, bl, accy[fc]);
          accy[fc] = MFMA(al, bh, accy[fc]);
        }
      }
    }
    __syncthreads();  // all waves finished reading XN before overwrite

    // ---- convert y fragments -> Y LDS (hi/lo) ----
#pragma unroll
    for (int fc = 0; fc < 4; ++fc)
#pragma unroll
      for (int r = 0; r < 4; ++r) {
        const int row = w * 16 + (lane >> 4) * 4 + r;
        const int col = fc * 16 + (lane & 15);
        unsigned short h, l;
        split2(accy[fc][r], h, l);
        const int idx = row * 64 + ((((col * 2) ^ ((row & 7) << 4))) >> 1);
        Yh[idx] = h;
        Yl[idx] = l;
      }
    // ---- stage xn f-tile for ALL 256 t rows into XN (hi/lo) ----
#pragma unroll
    for (int i = 0; i < 8; ++i) {
      const int g = tid + i * 512;
      const int r = g >> 4, c4 = g & 15;
      float4 xv = *(const float4*)(xc + (size_t)r * 512 + f0 + c4 * 4);
      ushort4 hv, lv;
      split2((xv.x - mean) * rstd, hv.x, lv.x);
      split2((xv.y - mean) * rstd, hv.y, lv.y);
      split2((xv.z - mean) * rstd, hv.z, lv.z);
      split2((xv.w - mean) * rstd, hv.w, lv.w);
      *(ushort4*)&XNh[swz8(r, c4)] = hv;
      *(ushort4*)&XNl[swz8(r, c4)] = lv;
    }
    __syncthreads();  // Y + XN(f-tile) visible to all
    // ---- phase 2: z += y · xn_f^T ----
#pragma unroll
    for (int ks = 0; ks < 2; ++ks) {
      bf16x8 ah = ldfrag(Yh, w * 16 + (lane & 15), ks, lane);
      bf16x8 al = ldfrag(Yl, w * 16 + (lane & 15), ks, lane);
#pragma unroll
      for (int ct = 0; ct < 16; ++ct) {
        bf16x8 bh = ldfrag(XNh, ct * 16 + (lane & 15), ks, lane);
        bf16x8 bl = ldfrag(XNl, ct * 16 + (lane & 15), ks, lane);
        accz[ct] = MFMA(ah, bh, accz[ct]);
        accz[ct] = MFMA(ah, bl, accz[ct]);
        accz[ct] = MFMA(al, bh, accz[ct]);
      }
    }
  }
  // ---- store z * 1/sqrt(E) ----
  const float scale = 0.044194173824159216f;
#pragma unroll
  for (int ct = 0; ct < 16; ++ct)
#pragma unroll
    for (int r = 0; r < 4; ++r) {
      const int row = w * 16 + (lane >> 4) * 4 + r;
      prodc[(size_t)row * 256 + ct * 16 + (lane & 15)] = accz[ct][r] * scale;
    }
}

// ---------------- K3: softmax over channel dim ----------------
__global__ void k3_softmax(float* __restrict__ ws) {
  const int bid = blockIdx.x;  // b*256 + s
  const int b = bid >> 8, s = bid & 255;
  const int t = threadIdx.x;
  float* __restrict__ p =
      ws + PROD_F + (size_t)b * (512ull * 65536) + (size_t)s * 256 + t;
  float m = -3.4e38f;
#pragma unroll 8
  for (int cc = 0; cc < 512; ++cc) m = fmaxf(m, p[(size_t)cc * 65536]);
  float sum = 0.f;
#pragma unroll 4
  for (int cc = 0; cc < 512; ++cc) {
    const float ev = __expf(p[(size_t)cc * 65536] - m);
    p[(size_t)cc * 65536] = ev;
    sum += ev;
  }
  ws[4096 + (size_t)bid * 256 + t] = 1.0f / sum;
}

// ---------------- K4: out = sm·v + xn ----------------
__launch_bounds__(256)
__global__ void k4_pv(const float* __restrict__ x,
                      const unsigned short* __restrict__ vws,
                      const float* __restrict__ ws,
                      float* __restrict__ out) {
  __shared__ float smt[32 * 68];
  __shared__ float vt[32 * 260];
  const int bid = blockIdx.x;
  const int bc = bid >> 3;
  const int s0 = ((bid >> 1) & 3) * 64;
  const int f0 = (bid & 1) * 256;
  const int b = bc >> 9;
  const int c = bc & 511;
  const int tid = threadIdx.x;
  const int tr = tid >> 5, tc = tid & 31;
  const float* __restrict__ pexp = ws + PROD_F + (size_t)bc * 65536;
  const float* __restrict__ inv = ws + 4096 + (size_t)b * 65536;
  const unsigned short* __restrict__ vc = vws + (size_t)bc * (Sn * En);

  float acc[2][2][4][4] = {};

  for (int tt = 0; tt < 8; ++tt) {
    const int t0 = tt * 32;
#pragma unroll
    for (int k = 0; k < 8; ++k) {
      const int idx = tid + 256 * k;
      const int r = idx >> 5, tl = idx & 31;
      const size_t gi = (size_t)(s0 + r) * 256 + t0 + tl;
      smt[tl * 68 + r] = pexp[gi] * inv[gi];
    }
#pragma unroll
    for (int k = 0; k < 8; ++k) {
      const int idx = tid + 256 * k;
      const int tl = idx >> 6, g = idx & 63;
      const ushort4 vv = *(const ushort4*)(vc + (size_t)(t0 + tl) * En + f0 + g * 4);
      float4 vf;
      vf.x = bf2f(vv.x); vf.y = bf2f(vv.y); vf.z = bf2f(vv.z); vf.w = bf2f(vv.w);
      *(float4*)(vt + tl * 260 + g * 4) = vf;
    }
    __syncthreads();
#pragma unroll 2
    for (int tl = 0; tl < 32; ++tl) {
      const float4 sa = *(const float4*)(smt + tl * 68 + tr * 4);
      const float4 sb = *(const float4*)(smt + tl * 68 + 32 + tr * 4);
      const float4 va = *(const float4*)(vt + tl * 260 + tc * 4);
      const float4 vb = *(const float4*)(vt + tl * 260 + 128 + tc * 4);
      const float sv[8] = {sa.x, sa.y, sa.z, sa.w, sb.x, sb.y, sb.z, sb.w};
      const float vv[8] = {va.x, va.y, va.z, va.w, vb.x, vb.y, vb.z, vb.w};
#pragma unroll
      for (int i = 0; i < 8; ++i)
#pragma unroll
        for (int j = 0; j < 8; ++j)
          acc[i >> 2][j >> 2][i & 3][j & 3] += sv[i] * vv[j];
    }
    __syncthreads();
  }
  const float mean = ws[c], rstd = ws[512 + c];
#pragma unroll
  for (int rh = 0; rh < 2; ++rh)
#pragma unroll
    for (int i = 0; i < 4; ++i) {
      const int srow = s0 + rh * 32 + tr * 4 + i;
#pragma unroll
      for (int ch = 0; ch < 2; ++ch) {
        const size_t oi =
            (size_t)bc * (Sn * En) + (size_t)srow * En + f0 + ch * 128 + tc * 4;
        const float4 xv = *(const float4*)(x + oi);
        float4 st;
        st.x = acc[rh][ch][i][0] + (xv.x - mean) * rstd;
        st.y = acc[rh][ch][i][1] + (xv.y - mean) * rstd;
        st.z = acc[rh][ch][i][2] + (xv.z - mean) * rstd;
        st.w = acc[rh][ch][i][3] + (xv.w - mean) * rstd;
        *(float4*)(out + oi) = st;
      }
    }
}

extern "C" void kernel_launch(void* const* d_in, const int* in_sizes, int n_in,
                              void* d_out, int out_size, void* d_ws, size_t ws_size,
                              hipStream_t stream) {
  const float* x = (const float*)d_in[0];
  const float* Q = (const float*)d_in[1];
  const float* K = (const float*)d_in[2];
  const float* V = (const float*)d_in[3];
  float* out = (float*)d_out;
  float* ws = (float*)d_ws;
  unsigned short* vws = (unsigned short*)((char*)d_ws + V_B);
  unsigned short* ATh = (unsigned short*)((char*)d_ws + ATH_B);
  unsigned short* ATl = (unsigned short*)((char*)d_ws + ATL_B);
  unsigned short* VT  = (unsigned short*)((char*)d_ws + VT_B);
  if (ws_size < WS_NEEDED) {
    fprintf(stderr, "kernel_launch: ws_size %zu < needed %zu\n", ws_size, WS_NEEDED);
  }
  k1_stats<<<dim3(512), dim3(256), 0, stream>>>(x, ws);
  kA<<<dim3(512), dim3(256), 0, stream>>>(Q, K, V, ATh, ATl, VT);
  kv_proj<<<dim3(2048, 4), dim3(256), 0, stream>>>(x, VT, ws, vws);
  kscores<<<dim3(2048), dim3(512), 0, stream>>>(x, ATh, ATl, ws, (float*)((char*)d_ws + PROD_B));
  k3_softmax<<<dim3(512), dim3(256), 0, stream>>>(ws);
  k4_pv<<<dim3(8192), dim3(256), 0, stream>>>(x, vws, ws, out);
}

// Round 3
// 2534.547 us; speedup vs baseline: 11.2589x; 1.0365x over previous
//
#include <hip/hip_runtime.h>
#include <hip/hip_bf16.h>
#include <cstdio>

#define Bn 2
#define Cn 512
#define Sn 256
#define En 512

typedef __attribute__((ext_vector_type(8))) short bf16x8;
typedef __attribute__((ext_vector_type(4))) float f32x4;

// Workspace layout (bytes):
//   [0, 2048)        : mean[512] f32
//   [2048, 4096)     : rstd[512] f32
//   byte 1 MiB       : prod/sm f32 [1024][256][256]   (256 MiB)
//   byte 1MiB+256MiB : vT bf16 [1024][512 f][256 t]   (256 MiB)
//   then AT_hi, AT_lo, VT bf16 (512 KiB each)
static constexpr size_t PROD_B = (1ull << 20);
static constexpr size_t V_B    = PROD_B + (256ull << 20);
static constexpr size_t ATH_B  = V_B + (256ull << 20);
static constexpr size_t ATL_B  = ATH_B + (512ull << 10);
static constexpr size_t VT_B   = ATL_B + (512ull << 10);
static constexpr size_t WS_NEEDED = VT_B + (512ull << 10);

__device__ __forceinline__ unsigned short f2bf(float f) {
  union { __hip_bfloat16 h; unsigned short u; } cv;
  cv.h = __float2bfloat16(f);
  return cv.u;
}
__device__ __forceinline__ float bf2f(unsigned short u) {
  union { unsigned int i; float f; } cv;
  cv.i = ((unsigned int)u) << 16;
  return cv.f;
}
__device__ __forceinline__ void split2(float v, unsigned short& h, unsigned short& l) {
  h = f2bf(v);
  l = f2bf(v - bf2f(h));
}
// ushort index of a 4-element (8-byte) group at (row, col-group c4) in a [R][64] ushort
// LDS tile, XOR-swizzled (T2: byte ^= (row&7)<<4).
__device__ __forceinline__ int swz8(int row, int c4) {
  return row * 64 + ((((c4 * 8) ^ ((row & 7) << 4))) >> 1);
}
// MFMA fragment load: 8 bf16 along k from row `row`, k-chunk = ks*32 + (lane>>4)*8.
__device__ __forceinline__ bf16x8 ldfrag(const unsigned short* arr, int row, int ks, int lane) {
  const int byte = (ks * 64 + ((lane >> 4) << 4)) ^ ((row & 7) << 4);
  return *(const bf16x8*)((const char*)(arr + (size_t)row * 64) + byte);
}
__device__ __forceinline__ f32x4 MFMA(bf16x8 a, bf16x8 b, f32x4 c) {
  return __builtin_amdgcn_mfma_f32_16x16x32_bf16(a, b, c, 0, 0, 0);
}

// ---------------- K1: per-channel mean / rstd ----------------
__global__ void k1_stats(const float* __restrict__ x, float* __restrict__ ws) {
  const int c = blockIdx.x, tid = threadIdx.x;
  const float4* p0 = (const float4*)(x + (size_t)c * (Sn * En));
  const float4* p1 = (const float4*)(x + (size_t)(Cn + c) * (Sn * En));
  float s1 = 0.f, s2 = 0.f;
  for (int i = tid; i < (Sn * En / 4); i += 256) {
    float4 a = p0[i], b = p1[i];
    s1 += (a.x + a.y) + (a.z + a.w) + (b.x + b.y) + (b.z + b.w);
    s2 += (a.x * a.x + a.y * a.y) + (a.z * a.z + a.w * a.w) +
          (b.x * b.x + b.y * b.y) + (b.z * b.z + b.w * b.w);
  }
  __shared__ float r1[256], r2[256];
  r1[tid] = s1; r2[tid] = s2;
  __syncthreads();
  for (int off = 128; off > 0; off >>= 1) {
    if (tid < off) { r1[tid] += r1[tid + off]; r2[tid] += r2[tid + off]; }
    __syncthreads();
  }
  if (tid == 0) {
    const float n = (float)(2 * Sn * En);
    float mean = r1[0] / n;
    float var = r2[0] / n - mean * mean;
    ws[c] = mean;
    ws[512 + c] = 1.0f / sqrtf(var + 1e-5f);
  }
}

// ---------------- kA: AT = K·Q^T split hi/lo bf16; VT = V^T bf16 ----------------
__global__ void kA(const float* __restrict__ Q, const float* __restrict__ K,
                   const float* __restrict__ V, unsigned short* __restrict__ ATh,
                   unsigned short* __restrict__ ATl, unsigned short* __restrict__ VT) {
  const int f = blockIdx.x, tid = threadIdx.x;
  __shared__ float Kf[512];
  for (int i = tid; i < 512; i += 256) Kf[i] = K[(size_t)f * 512 + i];
  __syncthreads();
#pragma unroll
  for (int half = 0; half < 2; ++half) {
    const int e = tid + half * 256;
    const float* Qe = Q + (size_t)e * 512;
    float acc = 0.f;
    for (int t = 0; t < 512; t += 4) {
      float4 q = *(const float4*)(Qe + t);
      acc += q.x * Kf[t] + q.y * Kf[t + 1] + q.z * Kf[t + 2] + q.w * Kf[t + 3];
    }
    unsigned short h, l;
    split2(acc, h, l);
    ATh[(size_t)f * 512 + e] = h;
    ATl[(size_t)f * 512 + e] = l;
    VT[(size_t)f * 512 + e] = f2bf(V[(size_t)e * 512 + f]);
  }
}

// ---------------- kv_proj: vT[f][t] = sum_e VT[f][e] * xn[t][e]  (bf16 MFMA) --------
// grid 8192: (bc, f-quarter, t-half), 256 threads (4 waves), wave-tile 32f x 128t.
__launch_bounds__(256)
__global__ void kv_proj(const float* __restrict__ x, const unsigned short* __restrict__ VT,
                        const float* __restrict__ ws, unsigned short* __restrict__ vT_out) {
  __shared__ unsigned short VTs[128 * 64];
  __shared__ unsigned short XN[128 * 64];
  const int bid = blockIdx.x;
  const int L = (bid & 7) * 1024 + (bid >> 3);  // chunked XCD swizzle (8192 % 8 == 0)
  const int bc = L >> 3;
  const int fq = (L >> 1) & 3;
  const int th = L & 1;
  const int c = bc & 511;
  const float mean = ws[c], rstd = ws[512 + c];
  const int f0 = fq * 128, t0 = th * 128;
  const int tid = threadIdx.x, w = tid >> 6, lane = tid & 63;
  const float* xb = x + (size_t)bc * 131072;

  f32x4 acc[2][8];
#pragma unroll
  for (int i = 0; i < 2; ++i)
#pragma unroll
    for (int j = 0; j < 8; ++j) acc[i][j] = (f32x4){0.f, 0.f, 0.f, 0.f};

  for (int et = 0; et < 8; ++et) {
    const int e0 = et * 64;
    __syncthreads();
#pragma unroll
    for (int i = 0; i < 8; ++i) {  // stage VT rows f0..f0+127
      const int g = tid + i * 256;
      const int r = g >> 4, c4 = g & 15;
      *(ushort4*)&VTs[swz8(r, c4)] =
          *(const ushort4*)(VT + (size_t)(f0 + r) * 512 + e0 + c4 * 4);
    }
#pragma unroll
    for (int i = 0; i < 8; ++i) {  // stage xn rows t0..t0+127 (hi only)
      const int g = tid + i * 256;
      const int r = g >> 4, c4 = g & 15;
      float4 xv = *(const float4*)(xb + (size_t)(t0 + r) * 512 + e0 + c4 * 4);
      ushort4 hv;
      hv.x = f2bf((xv.x - mean) * rstd);
      hv.y = f2bf((xv.y - mean) * rstd);
      hv.z = f2bf((xv.z - mean) * rstd);
      hv.w = f2bf((xv.w - mean) * rstd);
      *(ushort4*)&XN[swz8(r, c4)] = hv;
    }
    __syncthreads();
#pragma unroll
    for (int ks = 0; ks < 2; ++ks) {
      bf16x8 a0 = ldfrag(VTs, w * 32 + (lane & 15), ks, lane);
      bf16x8 a1 = ldfrag(VTs, w * 32 + 16 + (lane & 15), ks, lane);
#pragma unroll
      for (int ct = 0; ct < 8; ++ct) {
        bf16x8 b = ldfrag(XN, ct * 16 + (lane & 15), ks, lane);
        acc[0][ct] = MFMA(a0, b, acc[0][ct]);
        acc[1][ct] = MFMA(a1, b, acc[1][ct]);
      }
    }
  }
#pragma unroll
  for (int rt = 0; rt < 2; ++rt)
#pragma unroll
    for (int ct = 0; ct < 8; ++ct)
#pragma unroll
      for (int r = 0; r < 4; ++r) {
        const int f = f0 + w * 32 + rt * 16 + (lane >> 4) * 4 + r;
        vT_out[(size_t)bc * 131072 + (size_t)f * 256 + t0 + ct * 16 + (lane & 15)] =
            f2bf(acc[rt][ct][r]);
      }
}

// ---------------- kscores: z = (xn·A)·xn^T / sqrt(E), split-bf16 3-MFMA ----------------
// grid 2048: (bc, s-half). 512 threads = 8 waves; wave w owns z rows w*16..w*16+15.
// LDS 80 KiB (XN region aliased between phase-1 e-slices and phase-2 t-half f-slices)
// -> 2 blocks/CU; launch_bounds caps VGPR at 128 for 4 waves/SIMD.
__launch_bounds__(512, 4)
__global__ void kscores(const float* __restrict__ x, const unsigned short* __restrict__ ATh_g,
                        const unsigned short* __restrict__ ATl_g, const float* __restrict__ ws,
                        float* __restrict__ prod) {
  __shared__ unsigned short XNh[128 * 64], XNl[128 * 64];  // 16 KiB each
  __shared__ unsigned short ATh[64 * 64], ATl[64 * 64];    // 8 KiB each
  __shared__ unsigned short Yh[128 * 64], Yl[128 * 64];    // 16 KiB each => 80 KiB
  const int bid = blockIdx.x;
  const int L = (bid & 7) * 256 + (bid >> 3);  // chunked XCD swizzle: s-halves co-XCD
  const int bc = L >> 1, half = L & 1;
  const int c = bc & 511;
  const float mean = ws[c], rstd = ws[512 + c];
  const float* xc = x + (size_t)bc * (Sn * En);
  const float* xr = xc + (size_t)half * 128 * 512;
  float* prodc = prod + (size_t)bc * 65536 + (size_t)half * 128 * 256;
  const int tid = threadIdx.x, w = tid >> 6, lane = tid & 63;

  f32x4 accz[16];
#pragma unroll
  for (int i = 0; i < 16; ++i) accz[i] = (f32x4){0.f, 0.f, 0.f, 0.f};

  for (int ft = 0; ft < 8; ++ft) {
    const int f0 = ft * 64;
    f32x4 accy[4];
#pragma unroll
    for (int i = 0; i < 4; ++i) accy[i] = (f32x4){0.f, 0.f, 0.f, 0.f};

    // ---- phase 1: y[128][64] = xn_rows · A[:, f0:f0+64] ----
    for (int et = 0; et < 8; ++et) {
      const int e0 = et * 64;
      __syncthreads();  // prior readers of XN/AT done
#pragma unroll
      for (int i = 0; i < 4; ++i) {  // stage xn s-rows (hi/lo)
        const int g = tid + i * 512;
        const int r = g >> 4, c4 = g & 15;
        float4 xv = *(const float4*)(xr + (size_t)r * 512 + e0 + c4 * 4);
        ushort4 hv, lv;
        split2((xv.x - mean) * rstd, hv.x, lv.x);
        split2((xv.y - mean) * rstd, hv.y, lv.y);
        split2((xv.z - mean) * rstd, hv.z, lv.z);
        split2((xv.w - mean) * rstd, hv.w, lv.w);
        *(ushort4*)&XNh[swz8(r, c4)] = hv;
        *(ushort4*)&XNl[swz8(r, c4)] = lv;
      }
#pragma unroll
      for (int i = 0; i < 2; ++i) {  // stage AT tile
        const int g = tid + i * 512;
        const int r = g >> 4, c4 = g & 15;
        *(ushort4*)&ATh[swz8(r, c4)] =
            *(const ushort4*)(ATh_g + (size_t)(f0 + r) * 512 + e0 + c4 * 4);
        *(ushort4*)&ATl[swz8(r, c4)] =
            *(const ushort4*)(ATl_g + (size_t)(f0 + r) * 512 + e0 + c4 * 4);
      }
      __syncthreads();
#pragma unroll
      for (int ks = 0; ks < 2; ++ks) {
        bf16x8 ah = ldfrag(XNh, w * 16 + (lane & 15), ks, lane);
        bf16x8 al = ldfrag(XNl, w * 16 + (lane & 15), ks, lane);
#pragma unroll
        for (int fc = 0; fc < 4; ++fc) {
          bf16x8 bh = ldfrag(ATh, fc * 16 + (lane & 15), ks, lane);
          bf16x8 bl = ldfrag(ATl, fc * 16 + (lane & 15), ks, lane);
          accy[fc] = MFMA(ah, bh, accy[fc]);
          accy[fc] = MFMA(ah, bl, accy[fc]);
          accy[fc] = MFMA(al, bh, accy[fc]);
        }
      }
    }
    __syncthreads();  // phase-1 MFMAs done before XN region is restaged

    // ---- y fragments -> Y LDS (hi/lo); wave-private rows, no barrier needed ----
#pragma unroll
    for (int fc = 0; fc < 4; ++fc)
#pragma unroll
      for (int r = 0; r < 4; ++r) {
        const int row = w * 16 + (lane >> 4) * 4 + r;
        const int col = fc * 16 + (lane & 15);
        unsigned short h, l;
        split2(accy[fc][r], h, l);
        const int idx = row * 64 + ((((col * 2) ^ ((row & 7) << 4))) >> 1);
        Yh[idx] = h;
        Yl[idx] = l;
      }
    // ---- phase 2: z += y · xn_f^T, two t-halves of 128 rows ----
#pragma unroll
    for (int th = 0; th < 2; ++th) {
#pragma unroll
      for (int i = 0; i < 4; ++i) {  // stage xn t-rows f-slice (hi/lo)
        const int g = tid + i * 512;
        const int r = g >> 4, c4 = g & 15;
        float4 xv = *(const float4*)(xc + (size_t)(th * 128 + r) * 512 + f0 + c4 * 4);
        ushort4 hv, lv;
        split2((xv.x - mean) * rstd, hv.x, lv.x);
        split2((xv.y - mean) * rstd, hv.y, lv.y);
        split2((xv.z - mean) * rstd, hv.z, lv.z);
        split2((xv.w - mean) * rstd, hv.w, lv.w);
        *(ushort4*)&XNh[swz8(r, c4)] = hv;
        *(ushort4*)&XNl[swz8(r, c4)] = lv;
      }
      __syncthreads();
#pragma unroll
      for (int ks = 0; ks < 2; ++ks) {
        bf16x8 ah = ldfrag(Yh, w * 16 + (lane & 15), ks, lane);
        bf16x8 al = ldfrag(Yl, w * 16 + (lane & 15), ks, lane);
#pragma unroll
        for (int ct = 0; ct < 8; ++ct) {
          bf16x8 bh = ldfrag(XNh, ct * 16 + (lane & 15), ks, lane);
          bf16x8 bl = ldfrag(XNl, ct * 16 + (lane & 15), ks, lane);
          accz[th * 8 + ct] = MFMA(ah, bh, accz[th * 8 + ct]);
          accz[th * 8 + ct] = MFMA(ah, bl, accz[th * 8 + ct]);
          accz[th * 8 + ct] = MFMA(al, bh, accz[th * 8 + ct]);
        }
      }
      __syncthreads();  // t-half reads done before XN restage / next ft
    }
  }
  const float scale = 0.044194173824159216f;  // 1/sqrt(512)
#pragma unroll
  for (int th = 0; th < 2; ++th)
#pragma unroll
    for (int ct = 0; ct < 8; ++ct)
#pragma unroll
      for (int r = 0; r < 4; ++r) {
        const int row = w * 16 + (lane >> 4) * 4 + r;
        prodc[(size_t)row * 256 + th * 128 + ct * 16 + (lane & 15)] =
            accz[th * 8 + ct][r] * scale;
      }
}

// ---------------- K3: cross-channel softmax, online max+sum, normalized in place ------
__global__ void k3_softmax(float* __restrict__ prodf) {
  const int bid = blockIdx.x;  // b*256 + s
  const int b = bid >> 8, s = bid & 255;
  const int t = threadIdx.x;
  float* __restrict__ p = prodf + (size_t)b * (512ull * 65536) + (size_t)s * 256 + t;
  float m = -3.4e38f, sum = 0.f;
#pragma unroll 8
  for (int cc = 0; cc < 512; ++cc) {
    const float v = p[(size_t)cc * 65536];
    if (v > m) { sum *= __expf(m - v); m = v; }
    sum += __expf(v - m);
  }
  const float inv = 1.0f / sum;
#pragma unroll 4
  for (int cc = 0; cc < 512; ++cc) {
    p[(size_t)cc * 65536] = __expf(p[(size_t)cc * 65536] - m) * inv;
  }
}

// ---------------- K4: out = sm·v + xn  (bf16 MFMA) ----------------
// grid 8192: (bc, s-half, f-quarter), 256 threads (4 waves), wave-tile 32s x 128f.
__launch_bounds__(256)
__global__ void k4_pv(const float* __restrict__ x, const unsigned short* __restrict__ vT,
                      const float* __restrict__ ws, const float* __restrict__ sm,
                      float* __restrict__ out) {
  __shared__ unsigned short SMs[128 * 64];
  __shared__ unsigned short VTs[128 * 64];
  const int bid = blockIdx.x;
  const int L = (bid & 7) * 1024 + (bid >> 3);  // chunked XCD swizzle
  const int bc = L >> 3;
  const int sh = (L >> 2) & 1;
  const int fh = L & 3;
  const int c = bc & 511;
  const float mean = ws[c], rstd = ws[512 + c];
  const int s0 = sh * 128, f0 = fh * 128;
  const float* smb = sm + (size_t)bc * 65536;
  const unsigned short* vtb = vT + (size_t)bc * 131072;
  const int tid = threadIdx.x, w = tid >> 6, lane = tid & 63;

  f32x4 acc[2][8];
#pragma unroll
  for (int i = 0; i < 2; ++i)
#pragma unroll
    for (int j = 0; j < 8; ++j) acc[i][j] = (f32x4){0.f, 0.f, 0.f, 0.f};

  for (int kt = 0; kt < 4; ++kt) {
    const int t0 = kt * 64;
    __syncthreads();
#pragma unroll
    for (int i = 0; i < 8; ++i) {  // stage sm tile [128 s][64 t] f32 -> bf16
      const int g = tid + i * 256;
      const int r = g >> 4, c4 = g & 15;
      float4 pv = *(const float4*)(smb + (size_t)(s0 + r) * 256 + t0 + c4 * 4);
      ushort4 hv;
      hv.x = f2bf(pv.x); hv.y = f2bf(pv.y); hv.z = f2bf(pv.z); hv.w = f2bf(pv.w);
      *(ushort4*)&SMs[swz8(r, c4)] = hv;
    }
#pragma unroll
    for (int i = 0; i < 8; ++i) {  // stage vT tile [128 f][64 t]
      const int g = tid + i * 256;
      const int r = g >> 4, c4 = g & 15;
      *(ushort4*)&VTs[swz8(r, c4)] =
          *(const ushort4*)(vtb + (size_t)(f0 + r) * 256 + t0 + c4 * 4);
    }
    __syncthreads();
#pragma unroll
    for (int ks = 0; ks < 2; ++ks) {
      bf16x8 a0 = ldfrag(SMs, w * 32 + (lane & 15), ks, lane);
      bf16x8 a1 = ldfrag(SMs, w * 32 + 16 + (lane & 15), ks, lane);
#pragma unroll
      for (int ct = 0; ct < 8; ++ct) {
        bf16x8 b = ldfrag(VTs, ct * 16 + (lane & 15), ks, lane);
        acc[0][ct] = MFMA(a0, b, acc[0][ct]);
        acc[1][ct] = MFMA(a1, b, acc[1][ct]);
      }
    }
  }
#pragma unroll
  for (int rt = 0; rt < 2; ++rt)
#pragma unroll
    for (int ct = 0; ct < 8; ++ct)
#pragma unroll
      for (int r = 0; r < 4; ++r) {
        const int srow = s0 + w * 32 + rt * 16 + (lane >> 4) * 4 + r;
        const int fcol = f0 + ct * 16 + (lane & 15);
        const size_t oi = (size_t)bc * 131072 + (size_t)srow * 512 + fcol;
        out[oi] = acc[rt][ct][r] + (x[oi] - mean) * rstd;
      }
}

extern "C" void kernel_launch(void* const* d_in, const int* in_sizes, int n_in,
                              void* d_out, int out_size, void* d_ws, size_t ws_size,
                              hipStream_t stream) {
  const float* x = (const float*)d_in[0];
  const float* Q = (const float*)d_in[1];
  const float* K = (const float*)d_in[2];
  const float* V = (const float*)d_in[3];
  float* out = (float*)d_out;
  float* ws = (float*)d_ws;
  float* prodf = (float*)((char*)d_ws + PROD_B);
  unsigned short* vT  = (unsigned short*)((char*)d_ws + V_B);
  unsigned short* ATh = (unsigned short*)((char*)d_ws + ATH_B);
  unsigned short* ATl = (unsigned short*)((char*)d_ws + ATL_B);
  unsigned short* VTm = (unsigned short*)((char*)d_ws + VT_B);
  if (ws_size < WS_NEEDED) {
    fprintf(stderr, "kernel_launch: ws_size %zu < needed %zu\n", ws_size, WS_NEEDED);
  }
  k1_stats<<<dim3(512), dim3(256), 0, stream>>>(x, ws);
  kA<<<dim3(512), dim3(256), 0, stream>>>(Q, K, V, ATh, ATl, VTm);
  kv_proj<<<dim3(8192), dim3(256), 0, stream>>>(x, VTm, ws, vT);
  kscores<<<dim3(2048), dim3(512), 0, stream>>>(x, ATh, ATl, ws, prodf);
  k3_softmax<<<dim3(512), dim3(256), 0, stream>>>(prodf);
  k4_pv<<<dim3(8192), dim3(256), 0, stream>>>(x, vT, ws, prodf, out);
}

// Round 4
// 2107.130 us; speedup vs baseline: 13.5426x; 1.2028x over previous
//
#include <hip/hip_runtime.h>
#include <hip/hip_bf16.h>
#include <cstdio>

#define Bn 2
#define Cn 512
#define Sn 256
#define En 512

typedef __attribute__((ext_vector_type(8))) short bf16x8;
typedef __attribute__((ext_vector_type(4))) float f32x4;

// Workspace layout (bytes):
//   [0, 2048)        : mean[512] f32 ; [2048,4096): rstd[512] f32
//   byte 1 MiB       : prod/sm f32 [1024][256][256]          (256 MiB)
//   byte 1MiB+256MiB : vT bf16 tiled [1024][4 fh][4 kt][128][64]  (256 MiB)
//   + ATh, ATl tiled [8 ft][8 et][64][64] bf16 (512 KiB each)
//   + VT tiled [4 fq][8 et][128][64] bf16 (512 KiB)
//   + (optional, if ws allows) XNh, XNl tiled [1024 bc][8 et][256][64] (256 MiB each)
static constexpr size_t PROD_B = (1ull << 20);
static constexpr size_t V_B    = PROD_B + (256ull << 20);
static constexpr size_t ATH_B  = V_B + (256ull << 20);
static constexpr size_t ATL_B  = ATH_B + (512ull << 10);
static constexpr size_t VT_B   = ATL_B + (512ull << 10);
static constexpr size_t WS_SMALL = VT_B + (512ull << 10);
static constexpr size_t XNH_B  = WS_SMALL;
static constexpr size_t XNL_B  = XNH_B + (256ull << 20);
static constexpr size_t WS_BIG = XNL_B + (256ull << 20);

__device__ __forceinline__ unsigned short f2bf(float f) {
  union { __hip_bfloat16 h; unsigned short u; } cv;
  cv.h = __float2bfloat16(f);
  return cv.u;
}
__device__ __forceinline__ float bf2f(unsigned short u) {
  union { unsigned int i; float f; } cv;
  cv.i = ((unsigned int)u) << 16;
  return cv.f;
}
__device__ __forceinline__ void split2(float v, unsigned short& h, unsigned short& l) {
  h = f2bf(v);
  l = f2bf(v - bf2f(h));
}
// ushort index of 4-elem group at (row, c4) in a [R][64] ushort LDS tile,
// XOR-swizzled (byte ^= (row&7)<<4).
__device__ __forceinline__ int swz8(int row, int c4) {
  return row * 64 + ((((c4 * 8) ^ ((row & 7) << 4))) >> 1);
}
// swizzled ushort index within a tile row for single element col (intra-4 offset kept).
__device__ __forceinline__ int swzc(int row, int col) {
  return row * 64 + ((col & 3) | ((col & 60) ^ ((row & 7) << 3)));
}
// MFMA fragment load: 8 bf16 along k from row `row`, k-chunk = ks*32 + (lane>>4)*8.
__device__ __forceinline__ bf16x8 ldfrag(const unsigned short* arr, int row, int ks, int lane) {
  const int byte = (ks * 64 + ((lane >> 4) << 4)) ^ ((row & 7) << 4);
  return *(const bf16x8*)((const char*)(arr + (size_t)row * 64) + byte);
}
__device__ __forceinline__ f32x4 MFMA(bf16x8 a, bf16x8 b, f32x4 c) {
  return __builtin_amdgcn_mfma_f32_16x16x32_bf16(a, b, c, 0, 0, 0);
}
// async global->LDS, 16B per lane; LDS dest = l + lane*16 (wave-uniform base).
__device__ __forceinline__ void glds16(const void* g, void* l) {
  __builtin_amdgcn_global_load_lds(
      (const __attribute__((address_space(1))) unsigned int*)g,
      (__attribute__((address_space(3))) unsigned int*)l, 16, 0, 0);
}
// stage nbytes (multiple of 1024) from pre-tiled global (LDS-linear order) into LDS.
__device__ __forceinline__ void stage_tile(const unsigned short* g, unsigned short* l,
                                           int nbytes, int wid, int lane, int nwaves) {
  const char* gb = (const char*)g;
  char* lb = (char*)l;
  for (int j = wid; j < (nbytes >> 10); j += nwaves)
    glds16(gb + j * 1024 + lane * 16, lb + j * 1024);
}

// ---------------- K1: per-channel mean / rstd ----------------
__global__ void k1_stats(const float* __restrict__ x, float* __restrict__ ws) {
  const int c = blockIdx.x, tid = threadIdx.x;
  const float4* p0 = (const float4*)(x + (size_t)c * (Sn * En));
  const float4* p1 = (const float4*)(x + (size_t)(Cn + c) * (Sn * En));
  float s1 = 0.f, s2 = 0.f;
  for (int i = tid; i < (Sn * En / 4); i += 256) {
    float4 a = p0[i], b = p1[i];
    s1 += (a.x + a.y) + (a.z + a.w) + (b.x + b.y) + (b.z + b.w);
    s2 += (a.x * a.x + a.y * a.y) + (a.z * a.z + a.w * a.w) +
          (b.x * b.x + b.y * b.y) + (b.z * b.z + b.w * b.w);
  }
  __shared__ float r1[256], r2[256];
  r1[tid] = s1; r2[tid] = s2;
  __syncthreads();
  for (int off = 128; off > 0; off >>= 1) {
    if (tid < off) { r1[tid] += r1[tid + off]; r2[tid] += r2[tid + off]; }
    __syncthreads();
  }
  if (tid == 0) {
    const float n = (float)(2 * Sn * En);
    float mean = r1[0] / n;
    float var = r2[0] / n - mean * mean;
    ws[c] = mean;
    ws[512 + c] = 1.0f / sqrtf(var + 1e-5f);
  }
}

// ---------------- kA: AT = K·Q^T split hi/lo bf16 (tiled); VT = V^T bf16 (tiled) ------
// AT tile layout: [ft][et][64 f][64 e] swizzled. VT: [fq][et][128 f][64 e] swizzled.
__global__ void kA(const float* __restrict__ Q, const float* __restrict__ K,
                   const float* __restrict__ V, unsigned short* __restrict__ ATh,
                   unsigned short* __restrict__ ATl, unsigned short* __restrict__ VT) {
  const int f = blockIdx.x, tid = threadIdx.x;
  __shared__ float Kf[512];
  for (int i = tid; i < 512; i += 256) Kf[i] = K[(size_t)f * 512 + i];
  __syncthreads();
  const int fr64 = f & 63;
  const size_t atbase = ((size_t)(f >> 6) * 8) * 4096 + (size_t)fr64 * 64;
  const size_t vtbase = ((size_t)(f >> 7) * 8) * 8192 + (size_t)(f & 127) * 64;
#pragma unroll
  for (int half = 0; half < 2; ++half) {
    const int e = tid + half * 256;
    const float* Qe = Q + (size_t)e * 512;
    float acc = 0.f;
    for (int t = 0; t < 512; t += 4) {
      float4 q = *(const float4*)(Qe + t);
      acc += q.x * Kf[t] + q.y * Kf[t + 1] + q.z * Kf[t + 2] + q.w * Kf[t + 3];
    }
    unsigned short h, l;
    split2(acc, h, l);
    const int et = e >> 6, ec = e & 63;
    const int swa = (ec & 3) | ((ec & 60) ^ ((fr64 & 7) << 3));
    ATh[atbase + (size_t)et * 4096 + swa] = h;
    ATl[atbase + (size_t)et * 4096 + swa] = l;
    const int swv = (ec & 3) | ((ec & 60) ^ ((f & 7) << 3));
    VT[vtbase + (size_t)et * 8192 + swv] = f2bf(V[(size_t)e * 512 + f]);
  }
}

// ---------------- kxn: pre-split xn into tiled+swizzled hi/lo bf16 ----------------
// XN tile layout per bc: [8 et][256 rows][64 cols] swizzled, rows = s/t index.
__global__ void kxn(const float* __restrict__ x, const float* __restrict__ ws,
                    unsigned short* __restrict__ XNh, unsigned short* __restrict__ XNl) {
  const int bid = blockIdx.x;  // (bc, half)
  const int bc = bid >> 1, half = bid & 1;
  const int c = bc & 511;
  const float mean = ws[c], rstd = ws[512 + c];
  const float* xb = x + (size_t)bc * 131072 + (size_t)half * 128 * 512;
  const int tid = threadIdx.x;
#pragma unroll 4
  for (int i = 0; i < 64; ++i) {
    const int g = tid + i * 256;       // 128 rows x 128 col-groups
    const int r = g >> 7, c4 = g & 127;
    const float4 xv = *(const float4*)(xb + (size_t)r * 512 + c4 * 4);
    ushort4 hv, lv;
    split2((xv.x - mean) * rstd, hv.x, lv.x);
    split2((xv.y - mean) * rstd, hv.y, lv.y);
    split2((xv.z - mean) * rstd, hv.z, lv.z);
    split2((xv.w - mean) * rstd, hv.w, lv.w);
    const int et = c4 >> 4, colt4 = c4 & 15;
    const int row = half * 128 + r;
    const size_t idx = ((size_t)(bc * 8 + et) * 256 + row) * 64 +
                       ((colt4 * 4) ^ ((row & 7) << 3));
    *(ushort4*)&XNh[idx] = hv;
    *(ushort4*)&XNl[idx] = lv;
  }
}

// ---------------- kv_proj: vT[f][t] = sum_e VT[f][e]*xn[t][e]  (bf16 MFMA) ----------
// grid 8192: (bc, fq, th). Output vT tiled [bc][fh][kt][128 f][64 t] swizzled.
template <bool PRE>
__launch_bounds__(256)
__global__ void kv_proj(const float* __restrict__ x, const unsigned short* __restrict__ VT,
                        const unsigned short* __restrict__ XNh_g,
                        const float* __restrict__ ws, unsigned short* __restrict__ vT_out) {
  __shared__ unsigned short VTs[128 * 64];
  __shared__ unsigned short XN[128 * 64];
  const int bid = blockIdx.x;
  const int L = (bid & 7) * 1024 + (bid >> 3);  // chunked XCD swizzle
  const int bc = L >> 3;
  const int fq = (L >> 1) & 3;
  const int th = L & 1;
  const int c = bc & 511;
  const float mean = ws[c], rstd = ws[512 + c];
  const int f0 = fq * 128, t0 = th * 128;
  const int tid = threadIdx.x, w = tid >> 6, lane = tid & 63;
  const float* xb = x + (size_t)bc * 131072;

  f32x4 acc[2][8];
#pragma unroll
  for (int i = 0; i < 2; ++i)
#pragma unroll
    for (int j = 0; j < 8; ++j) acc[i][j] = (f32x4){0.f, 0.f, 0.f, 0.f};

  for (int et = 0; et < 8; ++et) {
    const int e0 = et * 64;
    __syncthreads();
    stage_tile(VT + ((size_t)fq * 8 + et) * 8192, VTs, 16384, w, lane, 4);
    if (PRE) {
      stage_tile(XNh_g + ((size_t)(bc * 8 + et) * 256 + t0) * 64, XN, 16384, w, lane, 4);
    } else {
#pragma unroll
      for (int i = 0; i < 8; ++i) {
        const int g = tid + i * 256;
        const int r = g >> 4, c4 = g & 15;
        float4 xv = *(const float4*)(xb + (size_t)(t0 + r) * 512 + e0 + c4 * 4);
        ushort4 hv;
        hv.x = f2bf((xv.x - mean) * rstd);
        hv.y = f2bf((xv.y - mean) * rstd);
        hv.z = f2bf((xv.z - mean) * rstd);
        hv.w = f2bf((xv.w - mean) * rstd);
        *(ushort4*)&XN[swz8(r, c4)] = hv;
      }
    }
    __syncthreads();
#pragma unroll
    for (int ks = 0; ks < 2; ++ks) {
      bf16x8 a0 = ldfrag(VTs, w * 32 + (lane & 15), ks, lane);
      bf16x8 a1 = ldfrag(VTs, w * 32 + 16 + (lane & 15), ks, lane);
#pragma unroll
      for (int ct = 0; ct < 8; ++ct) {
        bf16x8 b = ldfrag(XN, ct * 16 + (lane & 15), ks, lane);
        acc[0][ct] = MFMA(a0, b, acc[0][ct]);
        acc[1][ct] = MFMA(a1, b, acc[1][ct]);
      }
    }
  }
#pragma unroll
  for (int rt = 0; rt < 2; ++rt)
#pragma unroll
    for (int ct = 0; ct < 8; ++ct)
#pragma unroll
      for (int r = 0; r < 4; ++r) {
        const int f = f0 + w * 32 + rt * 16 + (lane >> 4) * 4 + r;
        const int t = t0 + ct * 16 + (lane & 15);
        const size_t idx = (((size_t)bc * 4 + (f >> 7)) * 4 + (t >> 6)) * 8192 +
                           (size_t)(f & 127) * 64 +
                           ((t & 3) | ((t & 60) ^ ((f & 7) << 3)));
        vT_out[idx] = f2bf(acc[rt][ct][r]);
      }
}

// ---------------- kscores: z = (xn·A)·xn^T / sqrt(E), split-bf16 3-MFMA --------------
// grid 2048: (bc, s-half). 512 thr = 8 waves; LDS 80 KiB -> 2 blocks/CU (no VGPR cap!).
template <bool PRE>
__launch_bounds__(512)
__global__ void kscores(const float* __restrict__ x, const unsigned short* __restrict__ ATh_g,
                        const unsigned short* __restrict__ ATl_g,
                        const unsigned short* __restrict__ XNh_g,
                        const unsigned short* __restrict__ XNl_g,
                        const float* __restrict__ ws, float* __restrict__ prod) {
  __shared__ unsigned short XNh[128 * 64], XNl[128 * 64];  // 16 KiB each
  __shared__ unsigned short ATh[64 * 64], ATl[64 * 64];    // 8 KiB each
  __shared__ unsigned short Yh[128 * 64], Yl[128 * 64];    // 16 KiB each => 80 KiB
  const int bid = blockIdx.x;
  const int L = (bid & 7) * 256 + (bid >> 3);  // chunked XCD swizzle
  const int bc = L >> 1, half = L & 1;
  const int c = bc & 511;
  const float mean = ws[c], rstd = ws[512 + c];
  const float* xc = x + (size_t)bc * (Sn * En);
  const float* xr = xc + (size_t)half * 128 * 512;
  float* prodc = prod + (size_t)bc * 65536 + (size_t)half * 128 * 256;
  const int tid = threadIdx.x, w = tid >> 6, lane = tid & 63;

  f32x4 accz[16];
#pragma unroll
  for (int i = 0; i < 16; ++i) accz[i] = (f32x4){0.f, 0.f, 0.f, 0.f};

  for (int ft = 0; ft < 8; ++ft) {
    const int f0 = ft * 64;
    f32x4 accy[4];
#pragma unroll
    for (int i = 0; i < 4; ++i) accy[i] = (f32x4){0.f, 0.f, 0.f, 0.f};

    // ---- phase 1: y[128][64] = xn_rows · A[:, f0:f0+64] ----
    for (int et = 0; et < 8; ++et) {
      const int e0 = et * 64;
      __syncthreads();  // prior readers of XN/AT done
      if (PRE) {
        stage_tile(XNh_g + ((size_t)(bc * 8 + et) * 256 + half * 128) * 64, XNh,
                   16384, w, lane, 8);
        stage_tile(XNl_g + ((size_t)(bc * 8 + et) * 256 + half * 128) * 64, XNl,
                   16384, w, lane, 8);
      } else {
#pragma unroll
        for (int i = 0; i < 4; ++i) {
          const int g = tid + i * 512;
          const int r = g >> 4, c4 = g & 15;
          float4 xv = *(const float4*)(xr + (size_t)r * 512 + e0 + c4 * 4);
          ushort4 hv, lv;
          split2((xv.x - mean) * rstd, hv.x, lv.x);
          split2((xv.y - mean) * rstd, hv.y, lv.y);
          split2((xv.z - mean) * rstd, hv.z, lv.z);
          split2((xv.w - mean) * rstd, hv.w, lv.w);
          *(ushort4*)&XNh[swz8(r, c4)] = hv;
          *(ushort4*)&XNl[swz8(r, c4)] = lv;
        }
      }
      stage_tile(ATh_g + ((size_t)ft * 8 + et) * 4096, ATh, 8192, w, lane, 8);
      stage_tile(ATl_g + ((size_t)ft * 8 + et) * 4096, ATl, 8192, w, lane, 8);
      __syncthreads();
#pragma unroll
      for (int ks = 0; ks < 2; ++ks) {
        bf16x8 ah = ldfrag(XNh, w * 16 + (lane & 15), ks, lane);
        bf16x8 al = ldfrag(XNl, w * 16 + (lane & 15), ks, lane);
#pragma unroll
        for (int fc = 0; fc < 4; ++fc) {
          bf16x8 bh = ldfrag(ATh, fc * 16 + (lane & 15), ks, lane);
          bf16x8 bl = ldfrag(ATl, fc * 16 + (lane & 15), ks, lane);
          accy[fc] = MFMA(ah, bh, accy[fc]);
          accy[fc] = MFMA(ah, bl, accy[fc]);
          accy[fc] = MFMA(al, bh, accy[fc]);
        }
      }
    }
    __syncthreads();  // phase-1 MFMAs done before XN region restaged

    // ---- y fragments -> Y LDS (hi/lo); wave-private rows ----
#pragma unroll
    for (int fc = 0; fc < 4; ++fc)
#pragma unroll
      for (int r = 0; r < 4; ++r) {
        const int row = w * 16 + (lane >> 4) * 4 + r;
        const int col = fc * 16 + (lane & 15);
        unsigned short h, l;
        split2(accy[fc][r], h, l);
        const int idx = swzc(row, col);
        Yh[idx] = h;
        Yl[idx] = l;
      }
    // ---- phase 2: z += y · xn_f^T, two t-halves of 128 rows ----
#pragma unroll
    for (int th = 0; th < 2; ++th) {
      if (PRE) {
        stage_tile(XNh_g + ((size_t)(bc * 8 + ft) * 256 + th * 128) * 64, XNh,
                   16384, w, lane, 8);
        stage_tile(XNl_g + ((size_t)(bc * 8 + ft) * 256 + th * 128) * 64, XNl,
                   16384, w, lane, 8);
      } else {
#pragma unroll
        for (int i = 0; i < 4; ++i) {
          const int g = tid + i * 512;
          const int r = g >> 4, c4 = g & 15;
          float4 xv = *(const float4*)(xc + (size_t)(th * 128 + r) * 512 + f0 + c4 * 4);
          ushort4 hv, lv;
          split2((xv.x - mean) * rstd, hv.x, lv.x);
          split2((xv.y - mean) * rstd, hv.y, lv.y);
          split2((xv.z - mean) * rstd, hv.z, lv.z);
          split2((xv.w - mean) * rstd, hv.w, lv.w);
          *(ushort4*)&XNh[swz8(r, c4)] = hv;
          *(ushort4*)&XNl[swz8(r, c4)] = lv;
        }
      }
      __syncthreads();
#pragma unroll
      for (int ks = 0; ks < 2; ++ks) {
        bf16x8 ah = ldfrag(Yh, w * 16 + (lane & 15), ks, lane);
        bf16x8 al = ldfrag(Yl, w * 16 + (lane & 15), ks, lane);
#pragma unroll
        for (int ct = 0; ct < 8; ++ct) {
          bf16x8 bh = ldfrag(XNh, ct * 16 + (lane & 15), ks, lane);
          bf16x8 bl = ldfrag(XNl, ct * 16 + (lane & 15), ks, lane);
          accz[th * 8 + ct] = MFMA(ah, bh, accz[th * 8 + ct]);
          accz[th * 8 + ct] = MFMA(ah, bl, accz[th * 8 + ct]);
          accz[th * 8 + ct] = MFMA(al, bh, accz[th * 8 + ct]);
        }
      }
      __syncthreads();  // t-half reads done before XN restage / next ft
    }
  }
  const float scale = 0.044194173824159216f;  // 1/sqrt(512)
#pragma unroll
  for (int th = 0; th < 2; ++th)
#pragma unroll
    for (int ct = 0; ct < 8; ++ct)
#pragma unroll
      for (int r = 0; r < 4; ++r) {
        const int row = w * 16 + (lane >> 4) * 4 + r;
        prodc[(size_t)row * 256 + th * 128 + ct * 16 + (lane & 15)] =
            accz[th * 8 + ct][r] * scale;
      }
}

// ---------------- K3: cross-channel softmax, normalized in place ----------------
__global__ void k3_softmax(float* __restrict__ prodf) {
  const int bid = blockIdx.x;  // b*256 + s
  const int b = bid >> 8, s = bid & 255;
  const int t = threadIdx.x;
  float* __restrict__ p = prodf + (size_t)b * (512ull * 65536) + (size_t)s * 256 + t;
  float m = -3.4e38f, sum = 0.f;
#pragma unroll 8
  for (int cc = 0; cc < 512; ++cc) {
    const float v = p[(size_t)cc * 65536];
    if (v > m) { sum *= __expf(m - v); m = v; }
    sum += __expf(v - m);
  }
  const float inv = 1.0f / sum;
#pragma unroll 4
  for (int cc = 0; cc < 512; ++cc) {
    p[(size_t)cc * 65536] = __expf(p[(size_t)cc * 65536] - m) * inv;
  }
}

// ---------------- K4: out = sm·v + xn  (bf16 MFMA) ----------------
__launch_bounds__(256)
__global__ void k4_pv(const float* __restrict__ x, const unsigned short* __restrict__ vT,
                      const float* __restrict__ ws, const float* __restrict__ sm,
                      float* __restrict__ out) {
  __shared__ unsigned short SMs[128 * 64];
  __shared__ unsigned short VTs[128 * 64];
  const int bid = blockIdx.x;
  const int L = (bid & 7) * 1024 + (bid >> 3);  // chunked XCD swizzle
  const int bc = L >> 3;
  const int sh = (L >> 2) & 1;
  const int fh = L & 3;
  const int c = bc & 511;
  const float mean = ws[c], rstd = ws[512 + c];
  const int s0 = sh * 128, f0 = fh * 128;
  const float* smb = sm + (size_t)bc * 65536;
  const int tid = threadIdx.x, w = tid >> 6, lane = tid & 63;

  f32x4 acc[2][8];
#pragma unroll
  for (int i = 0; i < 2; ++i)
#pragma unroll
    for (int j = 0; j < 8; ++j) acc[i][j] = (f32x4){0.f, 0.f, 0.f, 0.f};

  for (int kt = 0; kt < 4; ++kt) {
    const int t0 = kt * 64;
    __syncthreads();
    stage_tile(vT + (((size_t)bc * 4 + fh) * 4 + kt) * 8192, VTs, 16384, w, lane, 4);
#pragma unroll
    for (int i = 0; i < 8; ++i) {  // stage sm tile [128 s][64 t] f32 -> bf16
      const int g = tid + i * 256;
      const int r = g >> 4, c4 = g & 15;
      float4 pv = *(const float4*)(smb + (size_t)(s0 + r) * 256 + t0 + c4 * 4);
      ushort4 hv;
      hv.x = f2bf(pv.x); hv.y = f2bf(pv.y); hv.z = f2bf(pv.z); hv.w = f2bf(pv.w);
      *(ushort4*)&SMs[swz8(r, c4)] = hv;
    }
    __syncthreads();
#pragma unroll
    for (int ks = 0; ks < 2; ++ks) {
      bf16x8 a0 = ldfrag(SMs, w * 32 + (lane & 15), ks, lane);
      bf16x8 a1 = ldfrag(SMs, w * 32 + 16 + (lane & 15), ks, lane);
#pragma unroll
      for (int ct = 0; ct < 8; ++ct) {
        bf16x8 b = ldfrag(VTs, ct * 16 + (lane & 15), ks, lane);
        acc[0][ct] = MFMA(a0, b, acc[0][ct]);
        acc[1][ct] = MFMA(a1, b, acc[1][ct]);
      }
    }
  }
#pragma unroll
  for (int rt = 0; rt < 2; ++rt)
#pragma unroll
    for (int ct = 0; ct < 8; ++ct)
#pragma unroll
      for (int r = 0; r < 4; ++r) {
        const int srow = s0 + w * 32 + rt * 16 + (lane >> 4) * 4 + r;
        const int fcol = f0 + ct * 16 + (lane & 15);
        const size_t oi = (size_t)bc * 131072 + (size_t)srow * 512 + fcol;
        out[oi] = acc[rt][ct][r] + (x[oi] - mean) * rstd;
      }
}

extern "C" void kernel_launch(void* const* d_in, const int* in_sizes, int n_in,
                              void* d_out, int out_size, void* d_ws, size_t ws_size,
                              hipStream_t stream) {
  const float* x = (const float*)d_in[0];
  const float* Q = (const float*)d_in[1];
  const float* K = (const float*)d_in[2];
  const float* V = (const float*)d_in[3];
  float* out = (float*)d_out;
  float* ws = (float*)d_ws;
  float* prodf = (float*)((char*)d_ws + PROD_B);
  unsigned short* vT   = (unsigned short*)((char*)d_ws + V_B);
  unsigned short* ATh  = (unsigned short*)((char*)d_ws + ATH_B);
  unsigned short* ATl  = (unsigned short*)((char*)d_ws + ATL_B);
  unsigned short* VTm  = (unsigned short*)((char*)d_ws + VT_B);
  unsigned short* XNh  = (unsigned short*)((char*)d_ws + XNH_B);
  unsigned short* XNl  = (unsigned short*)((char*)d_ws + XNL_B);
  if (ws_size < WS_SMALL) {
    fprintf(stderr, "kernel_launch: ws_size %zu < needed %zu\n", ws_size, WS_SMALL);
  }
  const bool big = ws_size >= WS_BIG;
  k1_stats<<<dim3(512), dim3(256), 0, stream>>>(x, ws);
  kA<<<dim3(512), dim3(256), 0, stream>>>(Q, K, V, ATh, ATl, VTm);
  if (big) {
    kxn<<<dim3(2048), dim3(256), 0, stream>>>(x, ws, XNh, XNl);
    kv_proj<true><<<dim3(8192), dim3(256), 0, stream>>>(x, VTm, XNh, ws, vT);
    kscores<true><<<dim3(2048), dim3(512), 0, stream>>>(x, ATh, ATl, XNh, XNl, ws, prodf);
  } else {
    kv_proj<false><<<dim3(8192), dim3(256), 0, stream>>>(x, VTm, XNh, ws, vT);
    kscores<false><<<dim3(2048), dim3(512), 0, stream>>>(x, ATh, ATl, XNh, XNl, ws, prodf);
  }
  k3_softmax<<<dim3(512), dim3(256), 0, stream>>>(prodf);
  k4_pv<<<dim3(8192), dim3(256), 0, stream>>>(x, vT, ws, prodf, out);
}

// Round 5
// 2076.250 us; speedup vs baseline: 13.7441x; 1.0149x over previous
//
#include <hip/hip_runtime.h>
#include <hip/hip_bf16.h>
#include <cstdio>

#define Bn 2
#define Cn 512
#define Sn 256
#define En 512

typedef __attribute__((ext_vector_type(8))) short bf16x8;
typedef __attribute__((ext_vector_type(4))) float f32x4;

// Workspace layout (bytes):
//   [0, 2048)        : mean[512] f32 ; [2048,4096): rstd[512] f32
//   byte 1 MiB       : prod f32 [1024][256][256]                   (256 MiB)
//   byte 1MiB+256MiB : vT bf16 tiled [1024][4 fh][4 kt][128][64]   (256 MiB)
//   + ATh, ATl tiled [8 ft][8 et][64][64] bf16 (512 KiB each)
//   + VT tiled [4 fq][8 et][128][64] bf16 (512 KiB)
//   + XNh, XNl tiled [1024 bc][8 et][256][64] bf16 (256 MiB each)
//   smT (bf16 sm, tiled [1024 bc][2 sh][4 kt][128][64]) ALIASES XNl (dead after kscores).
static constexpr size_t PROD_B = (1ull << 20);
static constexpr size_t V_B    = PROD_B + (256ull << 20);
static constexpr size_t ATH_B  = V_B + (256ull << 20);
static constexpr size_t ATL_B  = ATH_B + (512ull << 10);
static constexpr size_t VT_B   = ATL_B + (512ull << 10);
static constexpr size_t XNH_B  = VT_B + (512ull << 10);
static constexpr size_t XNL_B  = XNH_B + (256ull << 20);
static constexpr size_t WS_BIG = XNL_B + (256ull << 20);
static constexpr size_t SMT_B  = XNL_B;  // alias: XNl dead after kscores

__device__ __forceinline__ unsigned short f2bf(float f) {
  union { __hip_bfloat16 h; unsigned short u; } cv;
  cv.h = __float2bfloat16(f);
  return cv.u;
}
__device__ __forceinline__ float bf2f(unsigned short u) {
  union { unsigned int i; float f; } cv;
  cv.i = ((unsigned int)u) << 16;
  return cv.f;
}
__device__ __forceinline__ void split2(float v, unsigned short& h, unsigned short& l) {
  h = f2bf(v);
  l = f2bf(v - bf2f(h));
}
// swizzled ushort index for element (row, col) in a [R][64] tile (byte ^= (row&7)<<4).
__device__ __forceinline__ int swzc(int row, int col) {
  return row * 64 + ((col & 3) | ((col & 60) ^ ((row & 7) << 3)));
}
// MFMA fragment load: 8 bf16 along k from row `row`, k-chunk = ks*32 + (lane>>4)*8.
__device__ __forceinline__ bf16x8 ldfrag(const unsigned short* arr, int row, int ks, int lane) {
  const int byte = (ks * 64 + ((lane >> 4) << 4)) ^ ((row & 7) << 4);
  return *(const bf16x8*)((const char*)(arr + (size_t)row * 64) + byte);
}
__device__ __forceinline__ f32x4 MFMA(bf16x8 a, bf16x8 b, f32x4 c) {
  return __builtin_amdgcn_mfma_f32_16x16x32_bf16(a, b, c, 0, 0, 0);
}
__device__ __forceinline__ void glds16(const void* g, void* l) {
  __builtin_amdgcn_global_load_lds(
      (const __attribute__((address_space(1))) unsigned int*)g,
      (__attribute__((address_space(3))) unsigned int*)l, 16, 0, 0);
}
// stage nbytes (multiple of 1024) from pre-tiled global (LDS-linear order) into LDS.
__device__ __forceinline__ void stage_tile(const unsigned short* g, unsigned short* l,
                                           int nbytes, int wid, int lane, int nwaves) {
  const char* gb = (const char*)g;
  char* lb = (char*)l;
  for (int j = wid; j < (nbytes >> 10); j += nwaves)
    glds16(gb + j * 1024 + lane * 16, lb + j * 1024);
}

// ---------------- K1: per-channel mean / rstd ----------------
__global__ void k1_stats(const float* __restrict__ x, float* __restrict__ ws) {
  const int c = blockIdx.x, tid = threadIdx.x;
  const float4* p0 = (const float4*)(x + (size_t)c * (Sn * En));
  const float4* p1 = (const float4*)(x + (size_t)(Cn + c) * (Sn * En));
  float s1 = 0.f, s2 = 0.f;
  for (int i = tid; i < (Sn * En / 4); i += 256) {
    float4 a = p0[i], b = p1[i];
    s1 += (a.x + a.y) + (a.z + a.w) + (b.x + b.y) + (b.z + b.w);
    s2 += (a.x * a.x + a.y * a.y) + (a.z * a.z + a.w * a.w) +
          (b.x * b.x + b.y * b.y) + (b.z * b.z + b.w * b.w);
  }
  __shared__ float r1[256], r2[256];
  r1[tid] = s1; r2[tid] = s2;
  __syncthreads();
  for (int off = 128; off > 0; off >>= 1) {
    if (tid < off) { r1[tid] += r1[tid + off]; r2[tid] += r2[tid + off]; }
    __syncthreads();
  }
  if (tid == 0) {
    const float n = (float)(2 * Sn * En);
    float mean = r1[0] / n;
    float var = r2[0] / n - mean * mean;
    ws[c] = mean;
    ws[512 + c] = 1.0f / sqrtf(var + 1e-5f);
  }
}

// ---------------- kA: AT = K·Q^T split hi/lo bf16 (tiled); VT = V^T bf16 (tiled) ------
__global__ void kA(const float* __restrict__ Q, const float* __restrict__ K,
                   const float* __restrict__ V, unsigned short* __restrict__ ATh,
                   unsigned short* __restrict__ ATl, unsigned short* __restrict__ VT) {
  const int f = blockIdx.x, tid = threadIdx.x;
  __shared__ float Kf[512];
  for (int i = tid; i < 512; i += 256) Kf[i] = K[(size_t)f * 512 + i];
  __syncthreads();
  const int fr64 = f & 63;
  const size_t atbase = ((size_t)(f >> 6) * 8) * 4096 + (size_t)fr64 * 64;
  const size_t vtbase = ((size_t)(f >> 7) * 8) * 8192 + (size_t)(f & 127) * 64;
#pragma unroll
  for (int half = 0; half < 2; ++half) {
    const int e = tid + half * 256;
    const float* Qe = Q + (size_t)e * 512;
    float acc = 0.f;
    for (int t = 0; t < 512; t += 4) {
      float4 q = *(const float4*)(Qe + t);
      acc += q.x * Kf[t] + q.y * Kf[t + 1] + q.z * Kf[t + 2] + q.w * Kf[t + 3];
    }
    unsigned short h, l;
    split2(acc, h, l);
    const int et = e >> 6, ec = e & 63;
    const int swa = (ec & 3) | ((ec & 60) ^ ((fr64 & 7) << 3));
    ATh[atbase + (size_t)et * 4096 + swa] = h;
    ATl[atbase + (size_t)et * 4096 + swa] = l;
    const int swv = (ec & 3) | ((ec & 60) ^ ((f & 7) << 3));
    VT[vtbase + (size_t)et * 8192 + swv] = f2bf(V[(size_t)e * 512 + f]);
  }
}

// ---------------- kxn: pre-split xn into tiled+swizzled hi/lo bf16 ----------------
__global__ void kxn(const float* __restrict__ x, const float* __restrict__ ws,
                    unsigned short* __restrict__ XNh, unsigned short* __restrict__ XNl) {
  const int bid = blockIdx.x;  // (bc, half)
  const int bc = bid >> 1, half = bid & 1;
  const int c = bc & 511;
  const float mean = ws[c], rstd = ws[512 + c];
  const float* xb = x + (size_t)bc * 131072 + (size_t)half * 128 * 512;
  const int tid = threadIdx.x;
#pragma unroll 4
  for (int i = 0; i < 64; ++i) {
    const int g = tid + i * 256;       // 128 rows x 128 col-groups
    const int r = g >> 7, c4 = g & 127;
    const float4 xv = *(const float4*)(xb + (size_t)r * 512 + c4 * 4);
    ushort4 hv, lv;
    split2((xv.x - mean) * rstd, hv.x, lv.x);
    split2((xv.y - mean) * rstd, hv.y, lv.y);
    split2((xv.z - mean) * rstd, hv.z, lv.z);
    split2((xv.w - mean) * rstd, hv.w, lv.w);
    const int et = c4 >> 4, colt4 = c4 & 15;
    const int row = half * 128 + r;
    const size_t idx = ((size_t)(bc * 8 + et) * 256 + row) * 64 +
                       ((colt4 * 4) ^ ((row & 7) << 3));
    *(ushort4*)&XNh[idx] = hv;
    *(ushort4*)&XNl[idx] = lv;
  }
}

// ---------------- kv_proj: vT[f][t] = sum_e VT[f][e]*xn[t][e]  (dbuf pipeline) -------
__launch_bounds__(256)
__global__ void kv_proj(const unsigned short* __restrict__ VT,
                        const unsigned short* __restrict__ XNh_g,
                        unsigned short* __restrict__ vT_out) {
  __shared__ unsigned short BUF[2][16384];  // each: [VT 8192][XN 8192] = 32 KiB
  const int bid = blockIdx.x;
  const int L = (bid & 7) * 1024 + (bid >> 3);  // chunked XCD swizzle
  const int bc = L >> 3;
  const int fq = (L >> 1) & 3;
  const int th = L & 1;
  const int f0 = fq * 128, t0 = th * 128;
  const int tid = threadIdx.x, w = tid >> 6, lane = tid & 63;

  f32x4 acc[2][8];
#pragma unroll
  for (int i = 0; i < 2; ++i)
#pragma unroll
    for (int j = 0; j < 8; ++j) acc[i][j] = (f32x4){0.f, 0.f, 0.f, 0.f};

  stage_tile(VT + ((size_t)fq * 8 + 0) * 8192, &BUF[0][0], 16384, w, lane, 4);
  stage_tile(XNh_g + ((size_t)(bc * 8 + 0) * 256 + t0) * 64, &BUF[0][8192], 16384, w, lane, 4);
  __syncthreads();
#pragma unroll 1
  for (int et = 0; et < 8; ++et) {
    if (et < 7) {
      const int b = (et + 1) & 1;
      stage_tile(VT + ((size_t)fq * 8 + et + 1) * 8192, &BUF[b][0], 16384, w, lane, 4);
      stage_tile(XNh_g + ((size_t)(bc * 8 + et + 1) * 256 + t0) * 64, &BUF[b][8192],
                 16384, w, lane, 4);
    }
    const unsigned short* cb = &BUF[et & 1][0];
#pragma unroll
    for (int ks = 0; ks < 2; ++ks) {
      bf16x8 a0 = ldfrag(cb, w * 32 + (lane & 15), ks, lane);
      bf16x8 a1 = ldfrag(cb, w * 32 + 16 + (lane & 15), ks, lane);
#pragma unroll
      for (int ct = 0; ct < 8; ++ct) {
        bf16x8 b = ldfrag(cb + 8192, ct * 16 + (lane & 15), ks, lane);
        acc[0][ct] = MFMA(a0, b, acc[0][ct]);
        acc[1][ct] = MFMA(a1, b, acc[1][ct]);
      }
    }
    __syncthreads();
  }
#pragma unroll
  for (int rt = 0; rt < 2; ++rt)
#pragma unroll
    for (int ct = 0; ct < 8; ++ct)
#pragma unroll
      for (int r = 0; r < 4; ++r) {
        const int f = f0 + w * 32 + rt * 16 + (lane >> 4) * 4 + r;
        const int t = t0 + ct * 16 + (lane & 15);
        const size_t idx = (((size_t)bc * 4 + (f >> 7)) * 4 + (t >> 6)) * 8192 +
                           (size_t)(f & 127) * 64 +
                           ((t & 3) | ((t & 60) ^ ((f & 7) << 3)));
        vT_out[idx] = f2bf(acc[rt][ct][r]);
      }
}

// ---------------- kscores: z = (xn·A)·xn^T / sqrt(E), 80-iter dbuf pipeline ----------
// grid 2048: (bc, s-half). 512 thr = 8 waves. LDS = 2x48K stage dbuf + 32K Y = 128 KiB.
// iter m = ft*10 + sub: sub<8 -> phase-1 et=sub (stage XN s-rows + AT; y += xn*A),
// sub 8/9 -> phase-2 t-half (stage XN t-rows f-slice; z += y*xn^T). One barrier/iter.
__launch_bounds__(512)
__global__ void kscores(const unsigned short* __restrict__ ATh_g,
                        const unsigned short* __restrict__ ATl_g,
                        const unsigned short* __restrict__ XNh_g,
                        const unsigned short* __restrict__ XNl_g,
                        float* __restrict__ prod) {
  __shared__ unsigned short BUF[2][24576];  // [XNh 8192][XNl 8192][ATh 4096][ATl 4096]
  __shared__ unsigned short Yh[128 * 64], Yl[128 * 64];
  const int bid = blockIdx.x;
  const int L = (bid & 7) * 256 + (bid >> 3);  // chunked XCD swizzle: s-halves co-XCD
  const int bc = L >> 1, half = L & 1;
  float* prodc = prod + (size_t)bc * 65536 + (size_t)half * 128 * 256;
  const int tid = threadIdx.x, w = tid >> 6, lane = tid & 63;

  f32x4 accz[16];
#pragma unroll
  for (int i = 0; i < 16; ++i) accz[i] = (f32x4){0.f, 0.f, 0.f, 0.f};
  f32x4 accy[4];

  // stage slot m into buffer b
  auto stage_slot = [&](int m, int b) {
    const int ft = m / 10, sub = m - ft * 10;
    unsigned short* dst = &BUF[b][0];
    if (sub < 8) {
      stage_tile(XNh_g + ((size_t)(bc * 8 + sub) * 256 + half * 128) * 64, dst,
                 16384, w, lane, 8);
      stage_tile(XNl_g + ((size_t)(bc * 8 + sub) * 256 + half * 128) * 64, dst + 8192,
                 16384, w, lane, 8);
      stage_tile(ATh_g + ((size_t)ft * 8 + sub) * 4096, dst + 16384, 8192, w, lane, 8);
      stage_tile(ATl_g + ((size_t)ft * 8 + sub) * 4096, dst + 20480, 8192, w, lane, 8);
    } else {
      const int th = sub - 8;
      stage_tile(XNh_g + ((size_t)(bc * 8 + ft) * 256 + th * 128) * 64, dst,
                 16384, w, lane, 8);
      stage_tile(XNl_g + ((size_t)(bc * 8 + ft) * 256 + th * 128) * 64, dst + 8192,
                 16384, w, lane, 8);
    }
  };

  stage_slot(0, 0);
  __syncthreads();

#pragma unroll 1
  for (int m = 0; m < 80; ++m) {
    const int sub = m % 10;
    if (m < 79) stage_slot(m + 1, (m + 1) & 1);
    const unsigned short* cb = &BUF[m & 1][0];
    if (sub == 0) {
#pragma unroll
      for (int i = 0; i < 4; ++i) accy[i] = (f32x4){0.f, 0.f, 0.f, 0.f};
    }
    if (sub < 8) {
      // ---- phase 1: accy += xn_srows(et) · AT(ft,et)^T ----
#pragma unroll
      for (int ks = 0; ks < 2; ++ks) {
        bf16x8 ah = ldfrag(cb, w * 16 + (lane & 15), ks, lane);
        bf16x8 al = ldfrag(cb + 8192, w * 16 + (lane & 15), ks, lane);
#pragma unroll
        for (int fc = 0; fc < 4; ++fc) {
          bf16x8 bh = ldfrag(cb + 16384, fc * 16 + (lane & 15), ks, lane);
          bf16x8 bl = ldfrag(cb + 20480, fc * 16 + (lane & 15), ks, lane);
          accy[fc] = MFMA(ah, bh, accy[fc]);
          accy[fc] = MFMA(ah, bl, accy[fc]);
          accy[fc] = MFMA(al, bh, accy[fc]);
        }
      }
      if (sub == 7) {
        // y fragments -> Y LDS (hi/lo); wave-private rows, read after the barrier
#pragma unroll
        for (int fc = 0; fc < 4; ++fc)
#pragma unroll
          for (int r = 0; r < 4; ++r) {
            const int row = w * 16 + (lane >> 4) * 4 + r;
            const int col = fc * 16 + (lane & 15);
            unsigned short h, l;
            split2(accy[fc][r], h, l);
            const int idx = swzc(row, col);
            Yh[idx] = h;
            Yl[idx] = l;
          }
      }
    } else if (sub == 8) {
#pragma unroll
      for (int ks = 0; ks < 2; ++ks) {
        bf16x8 ah = ldfrag(Yh, w * 16 + (lane & 15), ks, lane);
        bf16x8 al = ldfrag(Yl, w * 16 + (lane & 15), ks, lane);
#pragma unroll
        for (int ct = 0; ct < 8; ++ct) {
          bf16x8 bh = ldfrag(cb, ct * 16 + (lane & 15), ks, lane);
          bf16x8 bl = ldfrag(cb + 8192, ct * 16 + (lane & 15), ks, lane);
          accz[ct] = MFMA(ah, bh, accz[ct]);
          accz[ct] = MFMA(ah, bl, accz[ct]);
          accz[ct] = MFMA(al, bh, accz[ct]);
        }
      }
    } else {
#pragma unroll
      for (int ks = 0; ks < 2; ++ks) {
        bf16x8 ah = ldfrag(Yh, w * 16 + (lane & 15), ks, lane);
        bf16x8 al = ldfrag(Yl, w * 16 + (lane & 15), ks, lane);
#pragma unroll
        for (int ct = 0; ct < 8; ++ct) {
          bf16x8 bh = ldfrag(cb, ct * 16 + (lane & 15), ks, lane);
          bf16x8 bl = ldfrag(cb + 8192, ct * 16 + (lane & 15), ks, lane);
          accz[8 + ct] = MFMA(ah, bh, accz[8 + ct]);
          accz[8 + ct] = MFMA(ah, bl, accz[8 + ct]);
          accz[8 + ct] = MFMA(al, bh, accz[8 + ct]);
        }
      }
    }
    __syncthreads();
  }

  const float scale = 0.044194173824159216f;  // 1/sqrt(512)
#pragma unroll
  for (int th = 0; th < 2; ++th)
#pragma unroll
    for (int ct = 0; ct < 8; ++ct)
#pragma unroll
      for (int r = 0; r < 4; ++r) {
        const int row = w * 16 + (lane >> 4) * 4 + r;
        prodc[(size_t)row * 256 + th * 128 + ct * 16 + (lane & 15)] =
            accz[th * 8 + ct][r] * scale;
      }
}

// ---------------- K3: cross-channel softmax -> bf16 sm in k4-tiled layout ----------
// block (b,s), 512 threads: t = tid&255, c-half = tid>>8. smT[bc][sh][kt][128][64] swz.
__launch_bounds__(512)
__global__ void k3_softmax(const float* __restrict__ prodf, unsigned short* __restrict__ smT) {
  const int bid = blockIdx.x;  // b*256 + s
  const int b = bid >> 8, s = bid & 255;
  const int tid = threadIdx.x;
  const int t = tid & 255, ch = tid >> 8;
  const float* __restrict__ p =
      prodf + (size_t)b * (512ull * 65536) + (size_t)s * 256 + t + (size_t)ch * 256 * 65536;
  float m = -3.4e38f, sum = 0.f;
#pragma unroll 4
  for (int cc = 0; cc < 256; ++cc) {
    const float v = p[(size_t)cc * 65536];
    if (v > m) { sum *= __expf(m - v); m = v; }
    sum += __expf(v - m);
  }
  __shared__ float Ms[2][256], Ss[2][256];
  Ms[ch][t] = m; Ss[ch][t] = sum;
  __syncthreads();
  const float mo = Ms[ch ^ 1][t], so = Ss[ch ^ 1][t];
  const float mm = fmaxf(m, mo);
  const float inv = 1.0f / (sum * __expf(m - mm) + so * __expf(mo - mm));
  const int sh = s >> 7, r = s & 127, kt = t >> 6, col = t & 63;
  const int cidx = r * 64 + ((col & 3) | ((col & 60) ^ ((r & 7) << 3)));
  const size_t tbase = ((size_t)b * 512 + ch * 256) * 2 + sh;
#pragma unroll 4
  for (int cc = 0; cc < 256; ++cc) {
    const float ev = __expf(p[(size_t)cc * 65536] - mm) * inv;
    smT[((tbase + (size_t)cc * 2) * 4 + kt) * 8192 + cidx] = f2bf(ev);
  }
}

// ---------------- K4: out = sm·v + xn  (bf16 MFMA, dbuf pipeline) ----------------
__launch_bounds__(256)
__global__ void k4_pv(const float* __restrict__ x, const unsigned short* __restrict__ vT,
                      const float* __restrict__ ws, const unsigned short* __restrict__ smT,
                      float* __restrict__ out) {
  __shared__ unsigned short BUF[2][16384];  // each: [SM 8192][VT 8192] = 32 KiB
  const int bid = blockIdx.x;
  const int L = (bid & 7) * 1024 + (bid >> 3);  // chunked XCD swizzle
  const int bc = L >> 3;
  const int sh = (L >> 2) & 1;
  const int fh = L & 3;
  const int c = bc & 511;
  const float mean = ws[c], rstd = ws[512 + c];
  const int s0 = sh * 128, f0 = fh * 128;
  const int tid = threadIdx.x, w = tid >> 6, lane = tid & 63;

  f32x4 acc[2][8];
#pragma unroll
  for (int i = 0; i < 2; ++i)
#pragma unroll
    for (int j = 0; j < 8; ++j) acc[i][j] = (f32x4){0.f, 0.f, 0.f, 0.f};

  stage_tile(smT + (((size_t)bc * 2 + sh) * 4 + 0) * 8192, &BUF[0][0], 16384, w, lane, 4);
  stage_tile(vT + (((size_t)bc * 4 + fh) * 4 + 0) * 8192, &BUF[0][8192], 16384, w, lane, 4);
  __syncthreads();
#pragma unroll 1
  for (int kt = 0; kt < 4; ++kt) {
    if (kt < 3) {
      const int b = (kt + 1) & 1;
      stage_tile(smT + (((size_t)bc * 2 + sh) * 4 + kt + 1) * 8192, &BUF[b][0],
                 16384, w, lane, 4);
      stage_tile(vT + (((size_t)bc * 4 + fh) * 4 + kt + 1) * 8192, &BUF[b][8192],
                 16384, w, lane, 4);
    }
    const unsigned short* cb = &BUF[kt & 1][0];
#pragma unroll
    for (int ks = 0; ks < 2; ++ks) {
      bf16x8 a0 = ldfrag(cb, w * 32 + (lane & 15), ks, lane);
      bf16x8 a1 = ldfrag(cb, w * 32 + 16 + (lane & 15), ks, lane);
#pragma unroll
      for (int ct = 0; ct < 8; ++ct) {
        bf16x8 b = ldfrag(cb + 8192, ct * 16 + (lane & 15), ks, lane);
        acc[0][ct] = MFMA(a0, b, acc[0][ct]);
        acc[1][ct] = MFMA(a1, b, acc[1][ct]);
      }
    }
    __syncthreads();
  }
#pragma unroll
  for (int rt = 0; rt < 2; ++rt)
#pragma unroll
    for (int ct = 0; ct < 8; ++ct)
#pragma unroll
      for (int r = 0; r < 4; ++r) {
        const int srow = s0 + w * 32 + rt * 16 + (lane >> 4) * 4 + r;
        const int fcol = f0 + ct * 16 + (lane & 15);
        const size_t oi = (size_t)bc * 131072 + (size_t)srow * 512 + fcol;
        out[oi] = acc[rt][ct][r] + (x[oi] - mean) * rstd;
      }
}

extern "C" void kernel_launch(void* const* d_in, const int* in_sizes, int n_in,
                              void* d_out, int out_size, void* d_ws, size_t ws_size,
                              hipStream_t stream) {
  const float* x = (const float*)d_in[0];
  const float* Q = (const float*)d_in[1];
  const float* K = (const float*)d_in[2];
  const float* V = (const float*)d_in[3];
  float* out = (float*)d_out;
  float* ws = (float*)d_ws;
  float* prodf = (float*)((char*)d_ws + PROD_B);
  unsigned short* vT   = (unsigned short*)((char*)d_ws + V_B);
  unsigned short* ATh  = (unsigned short*)((char*)d_ws + ATH_B);
  unsigned short* ATl  = (unsigned short*)((char*)d_ws + ATL_B);
  unsigned short* VTm  = (unsigned short*)((char*)d_ws + VT_B);
  unsigned short* XNh  = (unsigned short*)((char*)d_ws + XNH_B);
  unsigned short* XNl  = (unsigned short*)((char*)d_ws + XNL_B);
  unsigned short* smT  = (unsigned short*)((char*)d_ws + SMT_B);
  if (ws_size < WS_BIG) {
    fprintf(stderr, "kernel_launch: ws_size %zu < needed %zu — expect corruption\n",
            ws_size, WS_BIG);
  }
  k1_stats<<<dim3(512), dim3(256), 0, stream>>>(x, ws);
  kA<<<dim3(512), dim3(256), 0, stream>>>(Q, K, V, ATh, ATl, VTm);
  kxn<<<dim3(2048), dim3(256), 0, stream>>>(x, ws, XNh, XNl);
  kv_proj<<<dim3(8192), dim3(256), 0, stream>>>(VTm, XNh, vT);
  kscores<<<dim3(2048), dim3(512), 0, stream>>>(ATh, ATl, XNh, XNl, prodf);
  k3_softmax<<<dim3(512), dim3(512), 0, stream>>>(prodf, smT);
  k4_pv<<<dim3(8192), dim3(256), 0, stream>>>(x, vT, ws, smT, out);
}